// Round 1
// baseline (3397.803 us; speedup 1.0000x reference)
//
#include <hip/hip_runtime.h>

#define N_NODES 50000
#define R_REL   4
#define E_NNZ   800000
#define ED_EDGES 200000
#define H_DIM   128
#define L_DIM   64

// ---------------- workspace layout (bytes, all 256-aligned) ----------------
#define WS_RP    0u           // (4N+1) int = 800004 -> 800256
#define WS_CUR   800256u      // 4N int
#define WS_CNT   1600512u     // 4N int
#define WS_CCOL  2400768u     // 4E int = 12.8e6
#define WS_CVAL  15200768u    // 4E float
#define WS_SP    28000768u    // N*248 f32 = 49.6e6
#define WS_SF    77600768u    // N*148 f32 = 29.6e6
#define WS_SN    107200768u   // N*148 f32 = 29.6e6   (S region ends 136800768)
#define WS_Y     28000768u    // N*320 f32 = 64e6     (reuses S region after GEMM1)
#define WS_ZP    92000768u    // N*64 f32 = 12.8e6
#define WS_ZF    104800768u
#define WS_ZN    117600768u   //                      (ends 130400768 < 136800768 ok)
#define WS_HP    136800768u   // N*128 f32 = 25.6e6
#define WS_HF    162400768u
#define WS_HN    188000768u   // ends 213600768
#define WS_Z     136800768u   // reuses h_p after all GEMM2 done

// ---------------- CSR build ----------------
__global__ void zero_kernel(int* p, int n) {
    int i = blockIdx.x * blockDim.x + threadIdx.x;
    if (i < n) p[i] = 0;
}

__global__ void hist_kernel(const int* __restrict__ rows, int* __restrict__ counts) {
    int g = blockIdx.x * blockDim.x + threadIdx.x;
    if (g >= R_REL * E_NNZ) return;
    int r = g / E_NNZ;
    atomicAdd(&counts[r * N_NODES + rows[g]], 1);
}

#define SCAN_T 1024
__global__ void scan_kernel(const int* __restrict__ counts, int* __restrict__ rp,
                            int* __restrict__ cursor) {
    __shared__ int sums[SCAN_T];
    int t = threadIdx.x;
    const int total = R_REL * N_NODES;
    const int chunk = (total + SCAN_T - 1) / SCAN_T;
    int lo = t * chunk, hi = lo + chunk;
    if (hi > total) hi = total;
    int s = 0;
    for (int i = lo; i < hi; i++) s += counts[i];
    sums[t] = s;
    __syncthreads();
    for (int d = 1; d < SCAN_T; d <<= 1) {
        int v = (t >= d) ? sums[t - d] : 0;
        __syncthreads();
        sums[t] += v;
        __syncthreads();
    }
    int base = (t == 0) ? 0 : sums[t - 1];
    for (int i = lo; i < hi; i++) {
        rp[i] = base; cursor[i] = base;
        base += counts[i];
    }
    if (t == SCAN_T - 1) rp[total] = base;   // = 4E
}

__global__ void scatter_kernel(const int* __restrict__ rows, const int* __restrict__ cols,
                               const float* __restrict__ vals, int* __restrict__ cursor,
                               int* __restrict__ cse_col, float* __restrict__ cse_val) {
    int g = blockIdx.x * blockDim.x + threadIdx.x;
    if (g >= R_REL * E_NNZ) return;
    int r = g / E_NNZ;
    int p = atomicAdd(&cursor[r * N_NODES + rows[g]], 1);
    cse_col[p] = cols[g];
    cse_val[p] = vals[g];
}

// ---------------- layer-1 spmm: S_v[i, r*din+d] = sum_e val * x[col, d] ----
__global__ void spmm1_kernel(const float* __restrict__ x, const int* __restrict__ rp,
                             const int* __restrict__ cse_col, const float* __restrict__ cse_val,
                             float* __restrict__ S, int din) {
    int wave = threadIdx.x >> 6, lane = threadIdx.x & 63;
    int row = blockIdx.x * 4 + wave;
    if (row >= N_NODES) return;
    int sout = din * 4;
    for (int r = 0; r < R_REL; r++) {
        int e0 = rp[r * N_NODES + row], e1 = rp[r * N_NODES + row + 1];
        float acc = 0.f;
        if (lane < din) {
            for (int e = e0; e < e1; e++) {
                int col = cse_col[e];
                float val = cse_val[e];
                acc += val * x[col * din + lane];
            }
            S[row * sout + r * din + lane] = acc;
        }
    }
}

// ---------------- GEMM1: h = relu((x@Ws^T + sum_r S_r@Wr^T + btot)/5) ------
// tile 64 rows x 128 cols, 256 threads, thread = 8 rows x 4 cols
__launch_bounds__(256)
__global__ void gemm1_kernel(const float* __restrict__ x, const float* __restrict__ S,
                             const float* __restrict__ Ws, const float* __restrict__ bs,
                             const float* __restrict__ Wr, const float* __restrict__ br,
                             float* __restrict__ h, int din) {
    __shared__ float sA[64 * 63];      // [row][k], stride 63
    __shared__ float sW[62 * 132];     // [k][j], stride 132 (16B-aligned float4 reads)
    int t = threadIdx.x;
    int i0 = blockIdx.x * 64;
    int rg = t >> 5, cg = t & 31;
    float acc[8][4] = {};
    for (int s = 0; s < 5; s++) {
        const float* Aptr; int astride;
        if (s == 0) { Aptr = x; astride = din; }
        else        { Aptr = S + (s - 1) * din; astride = 4 * din; }
        const float* Wp = (s == 0) ? Ws : (Wr + (s - 1) * H_DIM * din);
        __syncthreads();
        for (int idx = t; idx < 64 * din; idx += 256) {
            int rr = idx / din, k = idx - rr * din;
            int grow = i0 + rr;
            sA[rr * 63 + k] = (grow < N_NODES) ? Aptr[grow * astride + k] : 0.f;
        }
        for (int idx = t; idx < H_DIM * din; idx += 256) {
            int j = idx / din, k = idx - j * din;
            sW[k * 132 + j] = Wp[j * din + k];
        }
        __syncthreads();
        for (int k = 0; k < din; k++) {
            float a[8];
            #pragma unroll
            for (int rr = 0; rr < 8; rr++) a[rr] = sA[(rg * 8 + rr) * 63 + k];
            float4 w = *(const float4*)&sW[k * 132 + cg * 4];
            #pragma unroll
            for (int rr = 0; rr < 8; rr++) {
                acc[rr][0] += a[rr] * w.x; acc[rr][1] += a[rr] * w.y;
                acc[rr][2] += a[rr] * w.z; acc[rr][3] += a[rr] * w.w;
            }
        }
    }
    int j0 = cg * 4;
    float btot[4];
    #pragma unroll
    for (int cc = 0; cc < 4; cc++) {
        float b = bs[j0 + cc];
        #pragma unroll
        for (int r = 0; r < R_REL; r++) b += br[r * H_DIM + j0 + cc];
        btot[cc] = b;
    }
    #pragma unroll
    for (int rr = 0; rr < 8; rr++) {
        int grow = i0 + rg * 8 + rr;
        if (grow < N_NODES) {
            float4 o;
            o.x = fmaxf((acc[rr][0] + btot[0]) * 0.2f, 0.f);
            o.y = fmaxf((acc[rr][1] + btot[1]) * 0.2f, 0.f);
            o.z = fmaxf((acc[rr][2] + btot[2]) * 0.2f, 0.f);
            o.w = fmaxf((acc[rr][3] + btot[3]) * 0.2f, 0.f);
            *(float4*)&h[grow * H_DIM + j0] = o;
        }
    }
}

// ---------------- GEMM2: Y[i, ct*64+j] = sum_k h[i,k] * W[j,k] -------------
// tile 128 rows x 64 cols, K=128 in 2 chunks, 256 threads, thread = 8x4
__launch_bounds__(256)
__global__ void gemm2_kernel(const float* __restrict__ h, const float* __restrict__ Ws2,
                             const float* __restrict__ Wr2, float* __restrict__ Y) {
    __shared__ float sA[128 * 65];
    __shared__ float sW[64 * 68];
    int t = threadIdx.x;
    int i0 = blockIdx.x * 128;
    int ct = blockIdx.y;                     // 0..4 (0=self, 1..4=relations)
    int rg = t >> 4, cg = t & 15;
    const float* Wp = (ct == 0) ? Ws2 : (Wr2 + (ct - 1) * 64 * H_DIM);
    float acc[8][4] = {};
    for (int kc = 0; kc < 2; kc++) {
        __syncthreads();
        for (int idx = t; idx < 128 * 64; idx += 256) {
            int rr = idx >> 6, k = idx & 63;
            int grow = i0 + rr;
            sA[rr * 65 + k] = (grow < N_NODES) ? h[grow * H_DIM + kc * 64 + k] : 0.f;
        }
        for (int idx = t; idx < 64 * 64; idx += 256) {
            int j = idx >> 6, k = idx & 63;
            sW[k * 68 + j] = Wp[j * H_DIM + kc * 64 + k];
        }
        __syncthreads();
        for (int k = 0; k < 64; k++) {
            float a[8];
            #pragma unroll
            for (int rr = 0; rr < 8; rr++) a[rr] = sA[(rg * 8 + rr) * 65 + k];
            float4 w = *(const float4*)&sW[k * 68 + cg * 4];
            #pragma unroll
            for (int rr = 0; rr < 8; rr++) {
                acc[rr][0] += a[rr] * w.x; acc[rr][1] += a[rr] * w.y;
                acc[rr][2] += a[rr] * w.z; acc[rr][3] += a[rr] * w.w;
            }
        }
    }
    #pragma unroll
    for (int rr = 0; rr < 8; rr++) {
        int grow = i0 + rg * 8 + rr;
        if (grow < N_NODES) {
            float4 o = make_float4(acc[rr][0], acc[rr][1], acc[rr][2], acc[rr][3]);
            *(float4*)&Y[(size_t)grow * 320 + ct * 64 + cg * 4] = o;
        }
    }
}

// ---------------- spmm2 + z_v: z_v = (Yself + sum_r A_r@Y_r + btot)/5 ------
__global__ void spmm2z_kernel(const float* __restrict__ Y, const int* __restrict__ rp,
                              const int* __restrict__ cse_col, const float* __restrict__ cse_val,
                              const float* __restrict__ bs2, const float* __restrict__ br2,
                              float* __restrict__ zv) {
    int wave = threadIdx.x >> 6, lane = threadIdx.x & 63;
    int row = blockIdx.x * 4 + wave;
    if (row >= N_NODES) return;
    float acc = Y[(size_t)row * 320 + lane] + bs2[lane];
    #pragma unroll
    for (int r = 0; r < R_REL; r++) acc += br2[r * 64 + lane];
    for (int r = 0; r < R_REL; r++) {
        int e0 = rp[r * N_NODES + row], e1 = rp[r * N_NODES + row + 1];
        const float* Yr = Y + (1 + r) * 64 + lane;
        for (int e = e0; e < e1; e++) {
            int col = cse_col[e];
            float val = cse_val[e];
            acc += val * Yr[(size_t)col * 320];
        }
    }
    zv[row * 64 + lane] = acc * 0.2f;
}

// ---------------- gated fusion ----------------
__global__ void fusion_kernel(const float* __restrict__ zp, const float* __restrict__ zf,
                              const float* __restrict__ zn, const float* __restrict__ gW,
                              const float* __restrict__ gb, float* __restrict__ z) {
    int wave = threadIdx.x >> 6, lane = threadIdx.x & 63;
    int n = blockIdx.x * 4 + wave;
    if (n >= N_NODES) return;
    float vp = zp[n * 64 + lane], vf = zf[n * 64 + lane], vn = zn[n * 64 + lane];
    float sp = vp * gW[lane], sf = vf * gW[64 + lane], sn = vn * gW[128 + lane];
    #pragma unroll
    for (int d = 32; d >= 1; d >>= 1) {
        sp += __shfl_xor(sp, d);
        sf += __shfl_xor(sf, d);
        sn += __shfl_xor(sn, d);
    }
    sp += gb[0]; sf += gb[1]; sn += gb[2];
    float m = fmaxf(sp, fmaxf(sf, sn));
    float ep = __expf(sp - m), ef = __expf(sf - m), en = __expf(sn - m);
    float inv = 1.f / (ep + ef + en);
    z[n * 64 + lane] = (ep * vp + ef * vf + en * vn) * inv;
}

// ---------------- edge decoder: thread per edge, W1 via uniform s_loads ----
__launch_bounds__(256)
__global__ void decoder_kernel(const float* __restrict__ z, const int* __restrict__ esrc,
                               const int* __restrict__ edst, const float* __restrict__ w1,
                               const float* __restrict__ b1, const float* __restrict__ w2,
                               const float* __restrict__ b2, float* __restrict__ out) {
    int e = blockIdx.x * blockDim.x + threadIdx.x;
    if (e >= ED_EDGES) return;
    const float* zs = z + (size_t)esrc[e] * 64;
    const float* zd = z + (size_t)edst[e] * 64;
    float hid[64];
    #pragma unroll
    for (int j = 0; j < 64; j++) hid[j] = b1[j];
    #pragma unroll 1
    for (int kc = 0; kc < 64; kc += 8) {
        float a[8], b[8], p[8], q[8];
        #pragma unroll
        for (int kk = 0; kk < 8; kk++) {
            a[kk] = zs[kc + kk]; b[kk] = zd[kc + kk];
            p[kk] = a[kk] * b[kk]; q[kk] = fabsf(a[kk] - b[kk]);
        }
        #pragma unroll
        for (int j = 0; j < 64; j++) {
            const float* wrow = w1 + j * 256 + kc;
            float s = hid[j];
            #pragma unroll
            for (int kk = 0; kk < 8; kk++) {
                s += a[kk] * wrow[kk] + b[kk] * wrow[64 + kk]
                   + p[kk] * wrow[128 + kk] + q[kk] * wrow[192 + kk];
            }
            hid[j] = s;
        }
    }
    float logit = b2[0];
    #pragma unroll
    for (int j = 0; j < 64; j++) logit += fmaxf(hid[j], 0.f) * w2[j];
    out[e] = logit;
}

// ---------------- host ----------------
extern "C" void kernel_launch(void* const* d_in, const int* in_sizes, int n_in,
                              void* d_out, int out_size, void* d_ws, size_t ws_size,
                              hipStream_t stream) {
    const float* x_p = (const float*)d_in[0];
    const float* x_f = (const float*)d_in[1];
    const float* x_n = (const float*)d_in[2];
    const float* p1_Ws = (const float*)d_in[3];  const float* p1_bs = (const float*)d_in[4];
    const float* p1_Wr = (const float*)d_in[5];  const float* p1_br = (const float*)d_in[6];
    const float* p2_Ws = (const float*)d_in[7];  const float* p2_bs = (const float*)d_in[8];
    const float* p2_Wr = (const float*)d_in[9];  const float* p2_br = (const float*)d_in[10];
    const float* f1_Ws = (const float*)d_in[11]; const float* f1_bs = (const float*)d_in[12];
    const float* f1_Wr = (const float*)d_in[13]; const float* f1_br = (const float*)d_in[14];
    const float* f2_Ws = (const float*)d_in[15]; const float* f2_bs = (const float*)d_in[16];
    const float* f2_Wr = (const float*)d_in[17]; const float* f2_br = (const float*)d_in[18];
    const float* n1_Ws = (const float*)d_in[19]; const float* n1_bs = (const float*)d_in[20];
    const float* n1_Wr = (const float*)d_in[21]; const float* n1_br = (const float*)d_in[22];
    const float* n2_Ws = (const float*)d_in[23]; const float* n2_bs = (const float*)d_in[24];
    const float* n2_Wr = (const float*)d_in[25]; const float* n2_br = (const float*)d_in[26];
    const float* gate_W = (const float*)d_in[27]; const float* gate_b = (const float*)d_in[28];
    const float* dec_W1 = (const float*)d_in[29]; const float* dec_b1 = (const float*)d_in[30];
    const float* dec_W2 = (const float*)d_in[31]; const float* dec_b2 = (const float*)d_in[32];
    const int*   adj_rows = (const int*)d_in[33];
    const int*   adj_cols = (const int*)d_in[34];
    const float* adj_vals = (const float*)d_in[35];
    const int*   edge_src = (const int*)d_in[36];
    const int*   edge_dst = (const int*)d_in[37];

    char* ws = (char*)d_ws;
    int*   rp      = (int*)(ws + WS_RP);
    int*   cursor  = (int*)(ws + WS_CUR);
    int*   counts  = (int*)(ws + WS_CNT);
    int*   cse_col = (int*)(ws + WS_CCOL);
    float* cse_val = (float*)(ws + WS_CVAL);
    float* S_p = (float*)(ws + WS_SP);
    float* S_f = (float*)(ws + WS_SF);
    float* S_n = (float*)(ws + WS_SN);
    float* Y   = (float*)(ws + WS_Y);
    float* z_p = (float*)(ws + WS_ZP);
    float* z_f = (float*)(ws + WS_ZF);
    float* z_n = (float*)(ws + WS_ZN);
    float* h_p = (float*)(ws + WS_HP);
    float* h_f = (float*)(ws + WS_HF);
    float* h_n = (float*)(ws + WS_HN);
    float* z   = (float*)(ws + WS_Z);
    float* out = (float*)d_out;

    // CSR build (shared across views/layers)
    zero_kernel<<<(R_REL * N_NODES + 255) / 256, 256, 0, stream>>>(counts, R_REL * N_NODES);
    hist_kernel<<<(R_REL * E_NNZ + 255) / 256, 256, 0, stream>>>(adj_rows, counts);
    scan_kernel<<<1, SCAN_T, 0, stream>>>(counts, rp, cursor);
    scatter_kernel<<<(R_REL * E_NNZ + 255) / 256, 256, 0, stream>>>(
        adj_rows, adj_cols, adj_vals, cursor, cse_col, cse_val);

    // layer-1 spmm (spmm in input dim: din < 128)
    spmm1_kernel<<<N_NODES / 4, 256, 0, stream>>>(x_p, rp, cse_col, cse_val, S_p, 62);
    spmm1_kernel<<<N_NODES / 4, 256, 0, stream>>>(x_f, rp, cse_col, cse_val, S_f, 37);
    spmm1_kernel<<<N_NODES / 4, 256, 0, stream>>>(x_n, rp, cse_col, cse_val, S_n, 37);

    // layer-1 GEMMs -> h_v (relu, /5, bias folded)
    int g1 = (N_NODES + 63) / 64;
    gemm1_kernel<<<g1, 256, 0, stream>>>(x_p, S_p, p1_Ws, p1_bs, p1_Wr, p1_br, h_p, 62);
    gemm1_kernel<<<g1, 256, 0, stream>>>(x_f, S_f, f1_Ws, f1_bs, f1_Wr, f1_br, h_f, 37);
    gemm1_kernel<<<g1, 256, 0, stream>>>(x_n, S_n, n1_Ws, n1_bs, n1_Wr, n1_br, h_n, 37);

    // layer 2 per view: GEMM2 (matmul-first) then spmm2+z (Y buffer reused)
    dim3 g2((N_NODES + 127) / 128, 5);
    gemm2_kernel<<<g2, 256, 0, stream>>>(h_p, p2_Ws, p2_Wr, Y);
    spmm2z_kernel<<<N_NODES / 4, 256, 0, stream>>>(Y, rp, cse_col, cse_val, p2_bs, p2_br, z_p);
    gemm2_kernel<<<g2, 256, 0, stream>>>(h_f, f2_Ws, f2_Wr, Y);
    spmm2z_kernel<<<N_NODES / 4, 256, 0, stream>>>(Y, rp, cse_col, cse_val, f2_bs, f2_br, z_f);
    gemm2_kernel<<<g2, 256, 0, stream>>>(h_n, n2_Ws, n2_Wr, Y);
    spmm2z_kernel<<<N_NODES / 4, 256, 0, stream>>>(Y, rp, cse_col, cse_val, n2_bs, n2_br, z_n);

    // gated fusion -> z
    fusion_kernel<<<N_NODES / 4, 256, 0, stream>>>(z_p, z_f, z_n, gate_W, gate_b, z);

    // edge decoder -> logits
    decoder_kernel<<<(ED_EDGES + 255) / 256, 256, 0, stream>>>(
        z, edge_src, edge_dst, dec_W1, dec_b1, dec_W2, dec_b2, out);
}

// Round 2
// 2612.749 us; speedup vs baseline: 1.3005x; 1.3005x over previous
//
#include <hip/hip_runtime.h>

#define N_NODES 50000
#define R_REL   4
#define E_NNZ   800000
#define ED_EDGES 200000
#define H_DIM   128
#define L_DIM   64

#define RN_TOTAL (R_REL * N_NODES)    // 200000
#define SCAN_BLK 196                  // ceil(200000/1024)

// ---------------- workspace layout (bytes, all 256-aligned) ----------------
#define WS_RP    0u           // (4N+1) int = 800004 -> 800256
#define WS_CUR   800256u      // 4N int
#define WS_CNT   1600512u     // 4N int
#define WS_BSUM  2400512u     // 256 int (block sums for scan)  -> 2401536
#define WS_CCOL  2401536u     // 4E int = 12.8e6
#define WS_CVAL  15201536u    // 4E float
#define WS_SP    28001536u    // N*248 f32 = 49.6e6
#define WS_SF    77601536u    // N*148 f32 = 29.6e6
#define WS_SN    107201536u   // N*148 f32 = 29.6e6   (S region ends 136801536)
#define WS_Y     28001536u    // N*320 f32 = 64e6     (reuses S region after GEMM1)
#define WS_ZP    92001536u    // N*64 f32 = 12.8e6
#define WS_ZF    104801536u
#define WS_ZN    117601536u   //                      (ends 130401536 < 136801536 ok)
#define WS_HP    136801536u   // N*128 f32 = 25.6e6
#define WS_HF    162401536u
#define WS_HN    188001536u   // ends 213601536
#define WS_Z     136801536u   // reuses h_p after all GEMM2 done

// ---------------- CSR build ----------------
__global__ void zero_kernel(int* p, int n) {
    int i = blockIdx.x * blockDim.x + threadIdx.x;
    if (i < n) p[i] = 0;
}

__global__ void hist_kernel(const int* __restrict__ rows, int* __restrict__ counts) {
    int g = blockIdx.x * blockDim.x + threadIdx.x;
    if (g >= R_REL * E_NNZ) return;
    int r = g / E_NNZ;
    atomicAdd(&counts[r * N_NODES + rows[g]], 1);
}

// 3-phase coalesced scan over counts[200000] -> rp (exclusive), cursor, rp[200000]=total
__global__ void scan_part_kernel(const int* __restrict__ counts, int* __restrict__ bsum) {
    __shared__ int red[256];
    int base = blockIdx.x * 1024;
    int t = threadIdx.x;
    int s = 0;
    #pragma unroll
    for (int i = 0; i < 4; i++) {
        int idx = base + i * 256 + t;
        if (idx < RN_TOTAL) s += counts[idx];
    }
    red[t] = s; __syncthreads();
    for (int d = 128; d > 0; d >>= 1) {
        if (t < d) red[t] += red[t + d];
        __syncthreads();
    }
    if (t == 0) bsum[blockIdx.x] = red[0];
}

__global__ void scan_bsum_kernel(int* __restrict__ bsum, int* __restrict__ rp) {
    __shared__ int sh[256];
    int t = threadIdx.x;
    int v = (t < SCAN_BLK) ? bsum[t] : 0;
    sh[t] = v; __syncthreads();
    for (int d = 1; d < 256; d <<= 1) {
        int u = (t >= d) ? sh[t - d] : 0;
        __syncthreads();
        sh[t] += u;
        __syncthreads();
    }
    if (t < SCAN_BLK) bsum[t] = sh[t] - v;        // exclusive block offsets
    if (t == 255) rp[RN_TOTAL] = sh[255];         // grand total = 4E
}

__global__ void scan_final_kernel(const int* __restrict__ counts, const int* __restrict__ bsum,
                                  int* __restrict__ rp, int* __restrict__ cursor) {
    __shared__ int sh[256];
    int base = blockIdx.x * 1024;
    int t = threadIdx.x;
    int c[4]; int s = 0;
    #pragma unroll
    for (int i = 0; i < 4; i++) {
        int idx = base + t * 4 + i;
        c[i] = (idx < RN_TOTAL) ? counts[idx] : 0;
        s += c[i];
    }
    sh[t] = s; __syncthreads();
    for (int d = 1; d < 256; d <<= 1) {
        int u = (t >= d) ? sh[t - d] : 0;
        __syncthreads();
        sh[t] += u;
        __syncthreads();
    }
    int off = bsum[blockIdx.x] + sh[t] - s;       // exclusive prefix for this thread
    #pragma unroll
    for (int i = 0; i < 4; i++) {
        int idx = base + t * 4 + i;
        if (idx < RN_TOTAL) { rp[idx] = off; cursor[idx] = off; }
        off += c[i];
    }
}

__global__ void scatter_kernel(const int* __restrict__ rows, const int* __restrict__ cols,
                               const float* __restrict__ vals, int* __restrict__ cursor,
                               int* __restrict__ cse_col, float* __restrict__ cse_val) {
    int g = blockIdx.x * blockDim.x + threadIdx.x;
    if (g >= R_REL * E_NNZ) return;
    int r = g / E_NNZ;
    int p = atomicAdd(&cursor[r * N_NODES + rows[g]], 1);
    cse_col[p] = cols[g];
    cse_val[p] = vals[g];
}

// ---------------- layer-1 spmm, all 3 views in one pass --------------------
// S_v[i, r*din+d] = sum_e val * x_v[col, d]; edge metadata read once.
__global__ void spmm1_all_kernel(const float* __restrict__ xp, const float* __restrict__ xf,
                                 const float* __restrict__ xn,
                                 const int* __restrict__ rp, const int* __restrict__ cse_col,
                                 const float* __restrict__ cse_val,
                                 float* __restrict__ Sp, float* __restrict__ Sf,
                                 float* __restrict__ Sn) {
    int wave = threadIdx.x >> 6, lane = threadIdx.x & 63;
    int row = blockIdx.x * 4 + wave;
    if (row >= N_NODES) return;
    bool lp = lane < 62, lf = lane < 37;
    for (int r = 0; r < R_REL; r++) {
        int e0 = rp[r * N_NODES + row], e1 = rp[r * N_NODES + row + 1];
        float ap = 0.f, af = 0.f, an = 0.f;
        for (int e = e0; e < e1; e++) {
            int c = cse_col[e];
            float v = cse_val[e];
            if (lp) ap += v * xp[c * 62 + lane];
            if (lf) { af += v * xf[c * 37 + lane]; an += v * xn[c * 37 + lane]; }
        }
        if (lp) Sp[row * 248 + r * 62 + lane] = ap;
        if (lf) { Sf[row * 148 + r * 37 + lane] = af; Sn[row * 148 + r * 37 + lane] = an; }
    }
}

// ---------------- GEMM1: h = relu((x@Ws^T + sum_r S_r@Wr^T + btot)/5) ------
// tile 64 rows x 128 cols, 256 threads, thread = 8 rows x 4 cols
__launch_bounds__(256)
__global__ void gemm1_kernel(const float* __restrict__ x, const float* __restrict__ S,
                             const float* __restrict__ Ws, const float* __restrict__ bs,
                             const float* __restrict__ Wr, const float* __restrict__ br,
                             float* __restrict__ h, int din) {
    __shared__ float sA[64 * 63];      // [row][k], stride 63
    __shared__ float sW[62 * 132];     // [k][j], stride 132 (16B-aligned float4 reads)
    int t = threadIdx.x;
    int i0 = blockIdx.x * 64;
    int rg = t >> 5, cg = t & 31;
    float acc[8][4] = {};
    for (int s = 0; s < 5; s++) {
        const float* Aptr; int astride;
        if (s == 0) { Aptr = x; astride = din; }
        else        { Aptr = S + (s - 1) * din; astride = 4 * din; }
        const float* Wp = (s == 0) ? Ws : (Wr + (s - 1) * H_DIM * din);
        __syncthreads();
        for (int idx = t; idx < 64 * din; idx += 256) {
            int rr = idx / din, k = idx - rr * din;
            int grow = i0 + rr;
            sA[rr * 63 + k] = (grow < N_NODES) ? Aptr[grow * astride + k] : 0.f;
        }
        for (int idx = t; idx < H_DIM * din; idx += 256) {
            int j = idx / din, k = idx - j * din;
            sW[k * 132 + j] = Wp[j * din + k];
        }
        __syncthreads();
        for (int k = 0; k < din; k++) {
            float a[8];
            #pragma unroll
            for (int rr = 0; rr < 8; rr++) a[rr] = sA[(rg * 8 + rr) * 63 + k];
            float4 w = *(const float4*)&sW[k * 132 + cg * 4];
            #pragma unroll
            for (int rr = 0; rr < 8; rr++) {
                acc[rr][0] += a[rr] * w.x; acc[rr][1] += a[rr] * w.y;
                acc[rr][2] += a[rr] * w.z; acc[rr][3] += a[rr] * w.w;
            }
        }
    }
    int j0 = cg * 4;
    float btot[4];
    #pragma unroll
    for (int cc = 0; cc < 4; cc++) {
        float b = bs[j0 + cc];
        #pragma unroll
        for (int r = 0; r < R_REL; r++) b += br[r * H_DIM + j0 + cc];
        btot[cc] = b;
    }
    #pragma unroll
    for (int rr = 0; rr < 8; rr++) {
        int grow = i0 + rg * 8 + rr;
        if (grow < N_NODES) {
            float4 o;
            o.x = fmaxf((acc[rr][0] + btot[0]) * 0.2f, 0.f);
            o.y = fmaxf((acc[rr][1] + btot[1]) * 0.2f, 0.f);
            o.z = fmaxf((acc[rr][2] + btot[2]) * 0.2f, 0.f);
            o.w = fmaxf((acc[rr][3] + btot[3]) * 0.2f, 0.f);
            *(float4*)&h[grow * H_DIM + j0] = o;
        }
    }
}

// ---------------- GEMM2: Y[i, ct*64+j] = sum_k h[i,k] * W[j,k] -------------
// tile 128 rows x 64 cols, K=128 in 2 chunks, 256 threads, thread = 8x4
__launch_bounds__(256)
__global__ void gemm2_kernel(const float* __restrict__ h, const float* __restrict__ Ws2,
                             const float* __restrict__ Wr2, float* __restrict__ Y) {
    __shared__ float sA[128 * 65];
    __shared__ float sW[64 * 68];
    int t = threadIdx.x;
    int i0 = blockIdx.x * 128;
    int ct = blockIdx.y;                     // 0..4 (0=self, 1..4=relations)
    int rg = t >> 4, cg = t & 15;
    const float* Wp = (ct == 0) ? Ws2 : (Wr2 + (ct - 1) * 64 * H_DIM);
    float acc[8][4] = {};
    for (int kc = 0; kc < 2; kc++) {
        __syncthreads();
        for (int idx = t; idx < 128 * 64; idx += 256) {
            int rr = idx >> 6, k = idx & 63;
            int grow = i0 + rr;
            sA[rr * 65 + k] = (grow < N_NODES) ? h[grow * H_DIM + kc * 64 + k] : 0.f;
        }
        for (int idx = t; idx < 64 * 64; idx += 256) {
            int j = idx >> 6, k = idx & 63;
            sW[k * 68 + j] = Wp[j * H_DIM + kc * 64 + k];
        }
        __syncthreads();
        for (int k = 0; k < 64; k++) {
            float a[8];
            #pragma unroll
            for (int rr = 0; rr < 8; rr++) a[rr] = sA[(rg * 8 + rr) * 65 + k];
            float4 w = *(const float4*)&sW[k * 68 + cg * 4];
            #pragma unroll
            for (int rr = 0; rr < 8; rr++) {
                acc[rr][0] += a[rr] * w.x; acc[rr][1] += a[rr] * w.y;
                acc[rr][2] += a[rr] * w.z; acc[rr][3] += a[rr] * w.w;
            }
        }
    }
    #pragma unroll
    for (int rr = 0; rr < 8; rr++) {
        int grow = i0 + rg * 8 + rr;
        if (grow < N_NODES) {
            float4 o = make_float4(acc[rr][0], acc[rr][1], acc[rr][2], acc[rr][3]);
            *(float4*)&Y[(size_t)grow * 320 + ct * 64 + cg * 4] = o;
        }
    }
}

// ---------------- spmm2 + z_v: z_v = (Yself + sum_r A_r@Y_r + btot)/5 ------
__global__ void spmm2z_kernel(const float* __restrict__ Y, const int* __restrict__ rp,
                              const int* __restrict__ cse_col, const float* __restrict__ cse_val,
                              const float* __restrict__ bs2, const float* __restrict__ br2,
                              float* __restrict__ zv) {
    int wave = threadIdx.x >> 6, lane = threadIdx.x & 63;
    int row = blockIdx.x * 4 + wave;
    if (row >= N_NODES) return;
    float acc = Y[(size_t)row * 320 + lane] + bs2[lane];
    #pragma unroll
    for (int r = 0; r < R_REL; r++) acc += br2[r * 64 + lane];
    for (int r = 0; r < R_REL; r++) {
        int e0 = rp[r * N_NODES + row], e1 = rp[r * N_NODES + row + 1];
        const float* Yr = Y + (1 + r) * 64 + lane;
        for (int e = e0; e < e1; e++) {
            int col = cse_col[e];
            float val = cse_val[e];
            acc += val * Yr[(size_t)col * 320];
        }
    }
    zv[row * 64 + lane] = acc * 0.2f;
}

// ---------------- gated fusion ----------------
__global__ void fusion_kernel(const float* __restrict__ zp, const float* __restrict__ zf,
                              const float* __restrict__ zn, const float* __restrict__ gW,
                              const float* __restrict__ gb, float* __restrict__ z) {
    int wave = threadIdx.x >> 6, lane = threadIdx.x & 63;
    int n = blockIdx.x * 4 + wave;
    if (n >= N_NODES) return;
    float vp = zp[n * 64 + lane], vf = zf[n * 64 + lane], vn = zn[n * 64 + lane];
    float sp = vp * gW[lane], sf = vf * gW[64 + lane], sn = vn * gW[128 + lane];
    #pragma unroll
    for (int d = 32; d >= 1; d >>= 1) {
        sp += __shfl_xor(sp, d);
        sf += __shfl_xor(sf, d);
        sn += __shfl_xor(sn, d);
    }
    sp += gb[0]; sf += gb[1]; sn += gb[2];
    float m = fmaxf(sp, fmaxf(sf, sn));
    float ep = __expf(sp - m), ef = __expf(sf - m), en = __expf(sn - m);
    float inv = 1.f / (ep + ef + en);
    z[n * 64 + lane] = (ep * vp + ef * vf + en * vn) * inv;
}

// ---------------- edge decoder: thread per edge, W1 via uniform s_loads ----
__launch_bounds__(256)
__global__ void decoder_kernel(const float* __restrict__ z, const int* __restrict__ esrc,
                               const int* __restrict__ edst, const float* __restrict__ w1,
                               const float* __restrict__ b1, const float* __restrict__ w2,
                               const float* __restrict__ b2, float* __restrict__ out) {
    int e = blockIdx.x * blockDim.x + threadIdx.x;
    if (e >= ED_EDGES) return;
    const float* zs = z + (size_t)esrc[e] * 64;
    const float* zd = z + (size_t)edst[e] * 64;
    float hid[64];
    #pragma unroll
    for (int j = 0; j < 64; j++) hid[j] = b1[j];
    #pragma unroll 1
    for (int kc = 0; kc < 64; kc += 8) {
        float a[8], b[8], p[8], q[8];
        #pragma unroll
        for (int kk = 0; kk < 8; kk++) {
            a[kk] = zs[kc + kk]; b[kk] = zd[kc + kk];
            p[kk] = a[kk] * b[kk]; q[kk] = fabsf(a[kk] - b[kk]);
        }
        #pragma unroll
        for (int j = 0; j < 64; j++) {
            const float* wrow = w1 + j * 256 + kc;
            float s = hid[j];
            #pragma unroll
            for (int kk = 0; kk < 8; kk++) {
                s += a[kk] * wrow[kk] + b[kk] * wrow[64 + kk]
                   + p[kk] * wrow[128 + kk] + q[kk] * wrow[192 + kk];
            }
            hid[j] = s;
        }
    }
    float logit = b2[0];
    #pragma unroll
    for (int j = 0; j < 64; j++) logit += fmaxf(hid[j], 0.f) * w2[j];
    out[e] = logit;
}

// ---------------- host ----------------
extern "C" void kernel_launch(void* const* d_in, const int* in_sizes, int n_in,
                              void* d_out, int out_size, void* d_ws, size_t ws_size,
                              hipStream_t stream) {
    const float* x_p = (const float*)d_in[0];
    const float* x_f = (const float*)d_in[1];
    const float* x_n = (const float*)d_in[2];
    const float* p1_Ws = (const float*)d_in[3];  const float* p1_bs = (const float*)d_in[4];
    const float* p1_Wr = (const float*)d_in[5];  const float* p1_br = (const float*)d_in[6];
    const float* p2_Ws = (const float*)d_in[7];  const float* p2_bs = (const float*)d_in[8];
    const float* p2_Wr = (const float*)d_in[9];  const float* p2_br = (const float*)d_in[10];
    const float* f1_Ws = (const float*)d_in[11]; const float* f1_bs = (const float*)d_in[12];
    const float* f1_Wr = (const float*)d_in[13]; const float* f1_br = (const float*)d_in[14];
    const float* f2_Ws = (const float*)d_in[15]; const float* f2_bs = (const float*)d_in[16];
    const float* f2_Wr = (const float*)d_in[17]; const float* f2_br = (const float*)d_in[18];
    const float* n1_Ws = (const float*)d_in[19]; const float* n1_bs = (const float*)d_in[20];
    const float* n1_Wr = (const float*)d_in[21]; const float* n1_br = (const float*)d_in[22];
    const float* n2_Ws = (const float*)d_in[23]; const float* n2_bs = (const float*)d_in[24];
    const float* n2_Wr = (const float*)d_in[25]; const float* n2_br = (const float*)d_in[26];
    const float* gate_W = (const float*)d_in[27]; const float* gate_b = (const float*)d_in[28];
    const float* dec_W1 = (const float*)d_in[29]; const float* dec_b1 = (const float*)d_in[30];
    const float* dec_W2 = (const float*)d_in[31]; const float* dec_b2 = (const float*)d_in[32];
    const int*   adj_rows = (const int*)d_in[33];
    const int*   adj_cols = (const int*)d_in[34];
    const float* adj_vals = (const float*)d_in[35];
    const int*   edge_src = (const int*)d_in[36];
    const int*   edge_dst = (const int*)d_in[37];

    char* ws = (char*)d_ws;
    int*   rp      = (int*)(ws + WS_RP);
    int*   cursor  = (int*)(ws + WS_CUR);
    int*   counts  = (int*)(ws + WS_CNT);
    int*   bsum    = (int*)(ws + WS_BSUM);
    int*   cse_col = (int*)(ws + WS_CCOL);
    float* cse_val = (float*)(ws + WS_CVAL);
    float* S_p = (float*)(ws + WS_SP);
    float* S_f = (float*)(ws + WS_SF);
    float* S_n = (float*)(ws + WS_SN);
    float* Y   = (float*)(ws + WS_Y);
    float* z_p = (float*)(ws + WS_ZP);
    float* z_f = (float*)(ws + WS_ZF);
    float* z_n = (float*)(ws + WS_ZN);
    float* h_p = (float*)(ws + WS_HP);
    float* h_f = (float*)(ws + WS_HF);
    float* h_n = (float*)(ws + WS_HN);
    float* z   = (float*)(ws + WS_Z);
    float* out = (float*)d_out;

    // CSR build (shared across views/layers)
    zero_kernel<<<(RN_TOTAL + 255) / 256, 256, 0, stream>>>(counts, RN_TOTAL);
    hist_kernel<<<(R_REL * E_NNZ + 255) / 256, 256, 0, stream>>>(adj_rows, counts);
    scan_part_kernel<<<SCAN_BLK, 256, 0, stream>>>(counts, bsum);
    scan_bsum_kernel<<<1, 256, 0, stream>>>(bsum, rp);
    scan_final_kernel<<<SCAN_BLK, 256, 0, stream>>>(counts, bsum, rp, cursor);
    scatter_kernel<<<(R_REL * E_NNZ + 255) / 256, 256, 0, stream>>>(
        adj_rows, adj_cols, adj_vals, cursor, cse_col, cse_val);

    // layer-1 spmm for all 3 views in one pass (edge metadata read once)
    spmm1_all_kernel<<<N_NODES / 4, 256, 0, stream>>>(
        x_p, x_f, x_n, rp, cse_col, cse_val, S_p, S_f, S_n);

    // layer-1 GEMMs -> h_v (relu, /5, bias folded)
    int g1 = (N_NODES + 63) / 64;
    gemm1_kernel<<<g1, 256, 0, stream>>>(x_p, S_p, p1_Ws, p1_bs, p1_Wr, p1_br, h_p, 62);
    gemm1_kernel<<<g1, 256, 0, stream>>>(x_f, S_f, f1_Ws, f1_bs, f1_Wr, f1_br, h_f, 37);
    gemm1_kernel<<<g1, 256, 0, stream>>>(x_n, S_n, n1_Ws, n1_bs, n1_Wr, n1_br, h_n, 37);

    // layer 2 per view: GEMM2 (matmul-first) then spmm2+z (Y buffer reused)
    dim3 g2((N_NODES + 127) / 128, 5);
    gemm2_kernel<<<g2, 256, 0, stream>>>(h_p, p2_Ws, p2_Wr, Y);
    spmm2z_kernel<<<N_NODES / 4, 256, 0, stream>>>(Y, rp, cse_col, cse_val, p2_bs, p2_br, z_p);
    gemm2_kernel<<<g2, 256, 0, stream>>>(h_f, f2_Ws, f2_Wr, Y);
    spmm2z_kernel<<<N_NODES / 4, 256, 0, stream>>>(Y, rp, cse_col, cse_val, f2_bs, f2_br, z_f);
    gemm2_kernel<<<g2, 256, 0, stream>>>(h_n, n2_Ws, n2_Wr, Y);
    spmm2z_kernel<<<N_NODES / 4, 256, 0, stream>>>(Y, rp, cse_col, cse_val, n2_bs, n2_br, z_n);

    // gated fusion -> z
    fusion_kernel<<<N_NODES / 4, 256, 0, stream>>>(z_p, z_f, z_n, gate_W, gate_b, z);

    // edge decoder -> logits
    decoder_kernel<<<(ED_EDGES + 255) / 256, 256, 0, stream>>>(
        z, edge_src, edge_dst, dec_W1, dec_b1, dec_W2, dec_b2, out);
}

// Round 3
// 2061.287 us; speedup vs baseline: 1.6484x; 1.2675x over previous
//
#include <hip/hip_runtime.h>

#define N_NODES 50000
#define R_REL   4
#define E_NNZ   800000
#define ED_EDGES 200000
#define H_DIM   128
#define L_DIM   64

#define RN_TOTAL (R_REL * N_NODES)    // 200000
#define SCAN_BLK 196                  // ceil(200000/1024)

// ---------------- workspace layout (bytes) ----------------
// lifetime-aware reuse; max offset 206401536 (< 213601536 proven safe R1)
#define WS_RP     0u           // (4N+1) int
#define WS_CUR    800256u
#define WS_CNT    1600512u
#define WS_BSUM   2400512u
#define WS_CCOL   2401536u     // 4E int
#define WS_CVAL   15201536u    // 4E float
#define WS_XPH    28001536u    // N*62 bf16 = 6.2e6
#define WS_XFNH   34201536u    // N*37*2 bf16 (f/n interleaved) = 7.4e6
#define WS_SP     41601536u    // N*248 f32 = 49.6e6 (ends 91201536)
#define WS_SF     91201536u    // N*148 f32 (ends 120801536)
#define WS_SN     120801536u   // N*148 f32 (ends 150401536)
#define WS_HP     150401536u   // N*128 f32 (ends 176001536)
#define WS_HF     176001536u   // N*128 f32 (ends 201601536)
#define WS_HN     41601536u    // reuses S_p (free after gemm1_p)
#define WS_YSP    67201536u    // N*64 f32 (S_p tail, free after gemm1_p)
#define WS_YRP    91201536u    // N*256 bf16 (S_f region, free after gemm1_f)
#define WS_YSF    116801536u   // N*64 f32
#define WS_YRF    129601536u   // N*256 bf16 (spills into h_p region, free after gemm2_p)
#define WS_YSN    155201536u   // N*64 f32 (h_p region)
#define WS_YRN    168001536u   // N*256 bf16 (h_p tail + h_f region, free after gemm2_f)
#define WS_Z      193601536u   // N*64 f32 (ends 206401536)

__device__ __forceinline__ ushort f2bf(float f) {
    unsigned u = __float_as_uint(f);
    unsigned r = (u + 0x7fffu + ((u >> 16) & 1u)) >> 16;   // RNE
    return (ushort)r;
}
__device__ __forceinline__ float bf2f(ushort u) {
    return __uint_as_float(((unsigned)u) << 16);
}

// ---------------- bf16 staging casts ----------------
__global__ void cast_x_kernel(const float* __restrict__ x, ushort* __restrict__ xh, int n) {
    int i = blockIdx.x * 256 + threadIdx.x;
    if (i < n) xh[i] = f2bf(x[i]);
}
__global__ void cast_xfn_kernel(const float* __restrict__ xf, const float* __restrict__ xn,
                                ushort* __restrict__ xfn, int n) {
    int i = blockIdx.x * 256 + threadIdx.x;
    if (i < n) { xfn[2 * i] = f2bf(xf[i]); xfn[2 * i + 1] = f2bf(xn[i]); }
}

// ---------------- CSR build ----------------
__global__ void zero_kernel(int* p, int n) {
    int i = blockIdx.x * blockDim.x + threadIdx.x;
    if (i < n) p[i] = 0;
}

__global__ void hist_kernel(const int* __restrict__ rows, int* __restrict__ counts) {
    int g = blockIdx.x * blockDim.x + threadIdx.x;
    if (g >= R_REL * E_NNZ) return;
    int r = g / E_NNZ;
    atomicAdd(&counts[r * N_NODES + rows[g]], 1);
}

__global__ void scan_part_kernel(const int* __restrict__ counts, int* __restrict__ bsum) {
    __shared__ int red[256];
    int base = blockIdx.x * 1024;
    int t = threadIdx.x;
    int s = 0;
    #pragma unroll
    for (int i = 0; i < 4; i++) {
        int idx = base + i * 256 + t;
        if (idx < RN_TOTAL) s += counts[idx];
    }
    red[t] = s; __syncthreads();
    for (int d = 128; d > 0; d >>= 1) {
        if (t < d) red[t] += red[t + d];
        __syncthreads();
    }
    if (t == 0) bsum[blockIdx.x] = red[0];
}

__global__ void scan_bsum_kernel(int* __restrict__ bsum, int* __restrict__ rp) {
    __shared__ int sh[256];
    int t = threadIdx.x;
    int v = (t < SCAN_BLK) ? bsum[t] : 0;
    sh[t] = v; __syncthreads();
    for (int d = 1; d < 256; d <<= 1) {
        int u = (t >= d) ? sh[t - d] : 0;
        __syncthreads();
        sh[t] += u;
        __syncthreads();
    }
    if (t < SCAN_BLK) bsum[t] = sh[t] - v;
    if (t == 255) rp[RN_TOTAL] = sh[255];
}

__global__ void scan_final_kernel(const int* __restrict__ counts, const int* __restrict__ bsum,
                                  int* __restrict__ rp, int* __restrict__ cursor) {
    __shared__ int sh[256];
    int base = blockIdx.x * 1024;
    int t = threadIdx.x;
    int c[4]; int s = 0;
    #pragma unroll
    for (int i = 0; i < 4; i++) {
        int idx = base + t * 4 + i;
        c[i] = (idx < RN_TOTAL) ? counts[idx] : 0;
        s += c[i];
    }
    sh[t] = s; __syncthreads();
    for (int d = 1; d < 256; d <<= 1) {
        int u = (t >= d) ? sh[t - d] : 0;
        __syncthreads();
        sh[t] += u;
        __syncthreads();
    }
    int off = bsum[blockIdx.x] + sh[t] - s;
    #pragma unroll
    for (int i = 0; i < 4; i++) {
        int idx = base + t * 4 + i;
        if (idx < RN_TOTAL) { rp[idx] = off; cursor[idx] = off; }
        off += c[i];
    }
}

__global__ void scatter_kernel(const int* __restrict__ rows, const int* __restrict__ cols,
                               const float* __restrict__ vals, int* __restrict__ cursor,
                               int* __restrict__ cse_col, float* __restrict__ cse_val) {
    int g = blockIdx.x * blockDim.x + threadIdx.x;
    if (g >= R_REL * E_NNZ) return;
    int r = g / E_NNZ;
    int p = atomicAdd(&cursor[r * N_NODES + rows[g]], 1);
    cse_col[p] = cols[g];
    cse_val[p] = vals[g];
}

// ---------------- layer-1 spmm, all 3 views, bf16 gathers ------------------
__global__ void spmm1_all_kernel(const ushort* __restrict__ xp, const ushort* __restrict__ xfn,
                                 const int* __restrict__ rp, const int* __restrict__ cse_col,
                                 const float* __restrict__ cse_val,
                                 float* __restrict__ Sp, float* __restrict__ Sf,
                                 float* __restrict__ Sn) {
    int wave = threadIdx.x >> 6, lane = threadIdx.x & 63;
    int row = blockIdx.x * 4 + wave;
    if (row >= N_NODES) return;
    bool lp = lane < 62, lf = lane < 37;
    for (int r = 0; r < R_REL; r++) {
        int e0 = rp[r * N_NODES + row], e1 = rp[r * N_NODES + row + 1];
        float ap = 0.f, af = 0.f, an = 0.f;
        for (int e = e0; e < e1; e++) {
            int c = cse_col[e];
            float v = cse_val[e];
            if (lp) ap += v * bf2f(xp[c * 62 + lane]);
            if (lf) {
                ushort2 u = *(const ushort2*)&xfn[2 * (c * 37 + lane)];
                af += v * bf2f(u.x);
                an += v * bf2f(u.y);
            }
        }
        if (lp) Sp[row * 248 + r * 62 + lane] = ap;
        if (lf) { Sf[row * 148 + r * 37 + lane] = af; Sn[row * 148 + r * 37 + lane] = an; }
    }
}

// ---------------- GEMM1: h = relu((x@Ws^T + sum_r S_r@Wr^T + btot)/5) ------
__launch_bounds__(256)
__global__ void gemm1_kernel(const float* __restrict__ x, const float* __restrict__ S,
                             const float* __restrict__ Ws, const float* __restrict__ bs,
                             const float* __restrict__ Wr, const float* __restrict__ br,
                             float* __restrict__ h, int din) {
    __shared__ float sA[64 * 63];
    __shared__ float sW[62 * 132];
    int t = threadIdx.x;
    int i0 = blockIdx.x * 64;
    int rg = t >> 5, cg = t & 31;
    float acc[8][4] = {};
    for (int s = 0; s < 5; s++) {
        const float* Aptr; int astride;
        if (s == 0) { Aptr = x; astride = din; }
        else        { Aptr = S + (s - 1) * din; astride = 4 * din; }
        const float* Wp = (s == 0) ? Ws : (Wr + (s - 1) * H_DIM * din);
        __syncthreads();
        for (int idx = t; idx < 64 * din; idx += 256) {
            int rr = idx / din, k = idx - rr * din;
            int grow = i0 + rr;
            sA[rr * 63 + k] = (grow < N_NODES) ? Aptr[grow * astride + k] : 0.f;
        }
        for (int idx = t; idx < H_DIM * din; idx += 256) {
            int j = idx / din, k = idx - j * din;
            sW[k * 132 + j] = Wp[j * din + k];
        }
        __syncthreads();
        for (int k = 0; k < din; k++) {
            float a[8];
            #pragma unroll
            for (int rr = 0; rr < 8; rr++) a[rr] = sA[(rg * 8 + rr) * 63 + k];
            float4 w = *(const float4*)&sW[k * 132 + cg * 4];
            #pragma unroll
            for (int rr = 0; rr < 8; rr++) {
                acc[rr][0] += a[rr] * w.x; acc[rr][1] += a[rr] * w.y;
                acc[rr][2] += a[rr] * w.z; acc[rr][3] += a[rr] * w.w;
            }
        }
    }
    int j0 = cg * 4;
    float btot[4];
    #pragma unroll
    for (int cc = 0; cc < 4; cc++) {
        float b = bs[j0 + cc];
        #pragma unroll
        for (int r = 0; r < R_REL; r++) b += br[r * H_DIM + j0 + cc];
        btot[cc] = b;
    }
    #pragma unroll
    for (int rr = 0; rr < 8; rr++) {
        int grow = i0 + rg * 8 + rr;
        if (grow < N_NODES) {
            float4 o;
            o.x = fmaxf((acc[rr][0] + btot[0]) * 0.2f, 0.f);
            o.y = fmaxf((acc[rr][1] + btot[1]) * 0.2f, 0.f);
            o.z = fmaxf((acc[rr][2] + btot[2]) * 0.2f, 0.f);
            o.w = fmaxf((acc[rr][3] + btot[3]) * 0.2f, 0.f);
            *(float4*)&h[grow * H_DIM + j0] = o;
        }
    }
}

// ---------------- GEMM2: Yself fp32 (ct=0), Yrel bf16 (ct=1..4) ------------
__launch_bounds__(256)
__global__ void gemm2_kernel(const float* __restrict__ h, const float* __restrict__ Ws2,
                             const float* __restrict__ Wr2, float* __restrict__ Yself,
                             ushort* __restrict__ Yrel) {
    __shared__ float sA[128 * 65];
    __shared__ float sW[64 * 68];
    int t = threadIdx.x;
    int i0 = blockIdx.x * 128;
    int ct = blockIdx.y;                     // 0..4 (0=self, 1..4=relations)
    int rg = t >> 4, cg = t & 15;
    const float* Wp = (ct == 0) ? Ws2 : (Wr2 + (ct - 1) * 64 * H_DIM);
    float acc[8][4] = {};
    for (int kc = 0; kc < 2; kc++) {
        __syncthreads();
        for (int idx = t; idx < 128 * 64; idx += 256) {
            int rr = idx >> 6, k = idx & 63;
            int grow = i0 + rr;
            sA[rr * 65 + k] = (grow < N_NODES) ? h[grow * H_DIM + kc * 64 + k] : 0.f;
        }
        for (int idx = t; idx < 64 * 64; idx += 256) {
            int j = idx >> 6, k = idx & 63;
            sW[k * 68 + j] = Wp[j * H_DIM + kc * 64 + k];
        }
        __syncthreads();
        for (int k = 0; k < 64; k++) {
            float a[8];
            #pragma unroll
            for (int rr = 0; rr < 8; rr++) a[rr] = sA[(rg * 8 + rr) * 65 + k];
            float4 w = *(const float4*)&sW[k * 68 + cg * 4];
            #pragma unroll
            for (int rr = 0; rr < 8; rr++) {
                acc[rr][0] += a[rr] * w.x; acc[rr][1] += a[rr] * w.y;
                acc[rr][2] += a[rr] * w.z; acc[rr][3] += a[rr] * w.w;
            }
        }
    }
    #pragma unroll
    for (int rr = 0; rr < 8; rr++) {
        int grow = i0 + rg * 8 + rr;
        if (grow < N_NODES) {
            if (ct == 0) {
                float4 o = make_float4(acc[rr][0], acc[rr][1], acc[rr][2], acc[rr][3]);
                *(float4*)&Yself[(size_t)grow * 64 + cg * 4] = o;
            } else {
                ushort4 o;
                o.x = f2bf(acc[rr][0]); o.y = f2bf(acc[rr][1]);
                o.z = f2bf(acc[rr][2]); o.w = f2bf(acc[rr][3]);
                *(ushort4*)&Yrel[(size_t)grow * 256 + (ct - 1) * 64 + cg * 4] = o;
            }
        }
    }
}

// ------- spmm2 (all 3 views) + bias + /5 + gated fusion, one pass ----------
__global__ void spmm2z_all_kernel(const float* __restrict__ Ysp, const ushort* __restrict__ Yrp,
                                  const float* __restrict__ Ysf, const ushort* __restrict__ Yrf,
                                  const float* __restrict__ Ysn, const ushort* __restrict__ Yrn,
                                  const int* __restrict__ rp, const int* __restrict__ cse_col,
                                  const float* __restrict__ cse_val,
                                  const float* __restrict__ p_bs, const float* __restrict__ p_br,
                                  const float* __restrict__ f_bs, const float* __restrict__ f_br,
                                  const float* __restrict__ n_bs, const float* __restrict__ n_br,
                                  const float* __restrict__ gW, const float* __restrict__ gb,
                                  float* __restrict__ z) {
    int wave = threadIdx.x >> 6, lane = threadIdx.x & 63;
    int row = blockIdx.x * 4 + wave;
    if (row >= N_NODES) return;
    float aP = Ysp[(size_t)row * 64 + lane] + p_bs[lane]
             + p_br[lane] + p_br[64 + lane] + p_br[128 + lane] + p_br[192 + lane];
    float aF = Ysf[(size_t)row * 64 + lane] + f_bs[lane]
             + f_br[lane] + f_br[64 + lane] + f_br[128 + lane] + f_br[192 + lane];
    float aN = Ysn[(size_t)row * 64 + lane] + n_bs[lane]
             + n_br[lane] + n_br[64 + lane] + n_br[128 + lane] + n_br[192 + lane];
    for (int r = 0; r < R_REL; r++) {
        int e0 = rp[r * N_NODES + row], e1 = rp[r * N_NODES + row + 1];
        const ushort* yp = Yrp + r * 64 + lane;
        const ushort* yf = Yrf + r * 64 + lane;
        const ushort* yn = Yrn + r * 64 + lane;
        for (int e = e0; e < e1; e++) {
            int c = cse_col[e];
            float v = cse_val[e];
            aP += v * bf2f(yp[(size_t)c * 256]);
            aF += v * bf2f(yf[(size_t)c * 256]);
            aN += v * bf2f(yn[(size_t)c * 256]);
        }
    }
    aP *= 0.2f; aF *= 0.2f; aN *= 0.2f;
    // gated fusion
    float sp = aP * gW[lane], sf = aF * gW[64 + lane], sn = aN * gW[128 + lane];
    #pragma unroll
    for (int d = 32; d >= 1; d >>= 1) {
        sp += __shfl_xor(sp, d);
        sf += __shfl_xor(sf, d);
        sn += __shfl_xor(sn, d);
    }
    sp += gb[0]; sf += gb[1]; sn += gb[2];
    float m = fmaxf(sp, fmaxf(sf, sn));
    float ep = __expf(sp - m), ef = __expf(sf - m), en = __expf(sn - m);
    float inv = 1.f / (ep + ef + en);
    z[row * 64 + lane] = (ep * aP + ef * aF + en * aN) * inv;
}

// ---------------- edge decoder ----------------
__launch_bounds__(256)
__global__ void decoder_kernel(const float* __restrict__ z, const int* __restrict__ esrc,
                               const int* __restrict__ edst, const float* __restrict__ w1,
                               const float* __restrict__ b1, const float* __restrict__ w2,
                               const float* __restrict__ b2, float* __restrict__ out) {
    int e = blockIdx.x * blockDim.x + threadIdx.x;
    if (e >= ED_EDGES) return;
    const float* zs = z + (size_t)esrc[e] * 64;
    const float* zd = z + (size_t)edst[e] * 64;
    float hid[64];
    #pragma unroll
    for (int j = 0; j < 64; j++) hid[j] = b1[j];
    #pragma unroll 1
    for (int kc = 0; kc < 64; kc += 8) {
        float a[8], b[8], p[8], q[8];
        #pragma unroll
        for (int kk = 0; kk < 8; kk++) {
            a[kk] = zs[kc + kk]; b[kk] = zd[kc + kk];
            p[kk] = a[kk] * b[kk]; q[kk] = fabsf(a[kk] - b[kk]);
        }
        #pragma unroll
        for (int j = 0; j < 64; j++) {
            const float* wrow = w1 + j * 256 + kc;
            float s = hid[j];
            #pragma unroll
            for (int kk = 0; kk < 8; kk++) {
                s += a[kk] * wrow[kk] + b[kk] * wrow[64 + kk]
                   + p[kk] * wrow[128 + kk] + q[kk] * wrow[192 + kk];
            }
            hid[j] = s;
        }
    }
    float logit = b2[0];
    #pragma unroll
    for (int j = 0; j < 64; j++) logit += fmaxf(hid[j], 0.f) * w2[j];
    out[e] = logit;
}

// ---------------- host ----------------
extern "C" void kernel_launch(void* const* d_in, const int* in_sizes, int n_in,
                              void* d_out, int out_size, void* d_ws, size_t ws_size,
                              hipStream_t stream) {
    const float* x_p = (const float*)d_in[0];
    const float* x_f = (const float*)d_in[1];
    const float* x_n = (const float*)d_in[2];
    const float* p1_Ws = (const float*)d_in[3];  const float* p1_bs = (const float*)d_in[4];
    const float* p1_Wr = (const float*)d_in[5];  const float* p1_br = (const float*)d_in[6];
    const float* p2_Ws = (const float*)d_in[7];  const float* p2_bs = (const float*)d_in[8];
    const float* p2_Wr = (const float*)d_in[9];  const float* p2_br = (const float*)d_in[10];
    const float* f1_Ws = (const float*)d_in[11]; const float* f1_bs = (const float*)d_in[12];
    const float* f1_Wr = (const float*)d_in[13]; const float* f1_br = (const float*)d_in[14];
    const float* f2_Ws = (const float*)d_in[15]; const float* f2_bs = (const float*)d_in[16];
    const float* f2_Wr = (const float*)d_in[17]; const float* f2_br = (const float*)d_in[18];
    const float* n1_Ws = (const float*)d_in[19]; const float* n1_bs = (const float*)d_in[20];
    const float* n1_Wr = (const float*)d_in[21]; const float* n1_br = (const float*)d_in[22];
    const float* n2_Ws = (const float*)d_in[23]; const float* n2_bs = (const float*)d_in[24];
    const float* n2_Wr = (const float*)d_in[25]; const float* n2_br = (const float*)d_in[26];
    const float* gate_W = (const float*)d_in[27]; const float* gate_b = (const float*)d_in[28];
    const float* dec_W1 = (const float*)d_in[29]; const float* dec_b1 = (const float*)d_in[30];
    const float* dec_W2 = (const float*)d_in[31]; const float* dec_b2 = (const float*)d_in[32];
    const int*   adj_rows = (const int*)d_in[33];
    const int*   adj_cols = (const int*)d_in[34];
    const float* adj_vals = (const float*)d_in[35];
    const int*   edge_src = (const int*)d_in[36];
    const int*   edge_dst = (const int*)d_in[37];

    char* ws = (char*)d_ws;
    int*    rp      = (int*)(ws + WS_RP);
    int*    cursor  = (int*)(ws + WS_CUR);
    int*    counts  = (int*)(ws + WS_CNT);
    int*    bsum    = (int*)(ws + WS_BSUM);
    int*    cse_col = (int*)(ws + WS_CCOL);
    float*  cse_val = (float*)(ws + WS_CVAL);
    ushort* xp_h    = (ushort*)(ws + WS_XPH);
    ushort* xfn_h   = (ushort*)(ws + WS_XFNH);
    float*  S_p = (float*)(ws + WS_SP);
    float*  S_f = (float*)(ws + WS_SF);
    float*  S_n = (float*)(ws + WS_SN);
    float*  h_p = (float*)(ws + WS_HP);
    float*  h_f = (float*)(ws + WS_HF);
    float*  h_n = (float*)(ws + WS_HN);
    float*  Ys_p = (float*)(ws + WS_YSP);  ushort* Yr_p = (ushort*)(ws + WS_YRP);
    float*  Ys_f = (float*)(ws + WS_YSF);  ushort* Yr_f = (ushort*)(ws + WS_YRF);
    float*  Ys_n = (float*)(ws + WS_YSN);  ushort* Yr_n = (ushort*)(ws + WS_YRN);
    float*  z   = (float*)(ws + WS_Z);
    float*  out = (float*)d_out;

    // bf16 staging of node features
    cast_x_kernel<<<(N_NODES * 62 + 255) / 256, 256, 0, stream>>>(x_p, xp_h, N_NODES * 62);
    cast_xfn_kernel<<<(N_NODES * 37 + 255) / 256, 256, 0, stream>>>(x_f, x_n, xfn_h, N_NODES * 37);

    // CSR build (shared across views/layers)
    zero_kernel<<<(RN_TOTAL + 255) / 256, 256, 0, stream>>>(counts, RN_TOTAL);
    hist_kernel<<<(R_REL * E_NNZ + 255) / 256, 256, 0, stream>>>(adj_rows, counts);
    scan_part_kernel<<<SCAN_BLK, 256, 0, stream>>>(counts, bsum);
    scan_bsum_kernel<<<1, 256, 0, stream>>>(bsum, rp);
    scan_final_kernel<<<SCAN_BLK, 256, 0, stream>>>(counts, bsum, rp, cursor);
    scatter_kernel<<<(R_REL * E_NNZ + 255) / 256, 256, 0, stream>>>(
        adj_rows, adj_cols, adj_vals, cursor, cse_col, cse_val);

    // layer-1 spmm for all 3 views, bf16 gathers
    spmm1_all_kernel<<<N_NODES / 4, 256, 0, stream>>>(
        xp_h, xfn_h, rp, cse_col, cse_val, S_p, S_f, S_n);

    // layer-1 GEMMs -> h_v (fp32)
    int g1 = (N_NODES + 63) / 64;
    gemm1_kernel<<<g1, 256, 0, stream>>>(x_p, S_p, p1_Ws, p1_bs, p1_Wr, p1_br, h_p, 62);
    gemm1_kernel<<<g1, 256, 0, stream>>>(x_f, S_f, f1_Ws, f1_bs, f1_Wr, f1_br, h_f, 37);
    gemm1_kernel<<<g1, 256, 0, stream>>>(x_n, S_n, n1_Ws, n1_bs, n1_Wr, n1_br, h_n, 37);

    // layer-2 GEMMs (matmul-first): Yself fp32 + Yrel bf16 per view
    dim3 g2((N_NODES + 127) / 128, 5);
    gemm2_kernel<<<g2, 256, 0, stream>>>(h_p, p2_Ws, p2_Wr, Ys_p, Yr_p);
    gemm2_kernel<<<g2, 256, 0, stream>>>(h_f, f2_Ws, f2_Wr, Ys_f, Yr_f);
    gemm2_kernel<<<g2, 256, 0, stream>>>(h_n, n2_Ws, n2_Wr, Ys_n, Yr_n);

    // spmm2 (all views) + bias + gated fusion -> z
    spmm2z_all_kernel<<<N_NODES / 4, 256, 0, stream>>>(
        Ys_p, Yr_p, Ys_f, Yr_f, Ys_n, Yr_n, rp, cse_col, cse_val,
        p2_bs, p2_br, f2_bs, f2_br, n2_bs, n2_br, gate_W, gate_b, z);

    // edge decoder -> logits
    decoder_kernel<<<(ED_EDGES + 255) / 256, 256, 0, stream>>>(
        z, edge_src, edge_dst, dec_W1, dec_b1, dec_W2, dec_b2, out);
}

// Round 4
// 1684.105 us; speedup vs baseline: 2.0176x; 1.2240x over previous
//
#include <hip/hip_runtime.h>

#define N_NODES 50000
#define R_REL   4
#define E_NNZ   800000
#define ED_EDGES 200000
#define H_DIM   128
#define L_DIM   64

#define RN_TOTAL (R_REL * N_NODES)    // 200000
#define SCAN_BLK 196                  // ceil(200000/1024)

// ---------------- workspace layout (bytes) ----------------
#define WS_RP     0u           // (4N+1) int
#define WS_CUR    800256u
#define WS_CNT    1600512u
#define WS_BSUM   2400512u
#define WS_CV     2401536u     // 4E int2 (col, val-bits) = 25.6e6 -> 28001536
#define WS_XALL   28001536u    // N * 192 ushort (384B/row, cache-aligned) -> 47201536
#define WS_SP     47201536u    // N*248 f32 -> 96801536
#define WS_SF     96801536u    // N*148 f32 -> 126401536
#define WS_SN     126401536u   // N*148 f32 -> 156001536
#define WS_HP     156001536u   // N*128 f32 -> 181601536
#define WS_HF     181601536u   // N*128 f32 -> 207201536
#define WS_HN     47201536u    // reuses S_p (free after gemm1_p) -> 72801536
#define WS_YSP    72801536u    // N*64 f32 (S_p tail) -> 85601536
#define WS_YRP    96801536u    // N*256 bf16 (S_f region, free after gemm1) -> 122401536
#define WS_YSF    122401536u   // N*64 f32 -> 135201536
#define WS_YRF    135201536u   // N*256 bf16 (S_n + h_p head; h_p free after gemm2_p) -> 160801536
#define WS_YSN    160801536u   // N*64 f32 (h_p region) -> 173601536
#define WS_YRN    173601536u   // N*256 bf16 (h_p tail + h_f; h_f free after gemm2_f) -> 199201536
#define WS_Z      199201536u   // N*64 f32 -> 212001536

__device__ __forceinline__ ushort f2bf(float f) {
    unsigned u = __float_as_uint(f);
    unsigned r = (u + 0x7fffu + ((u >> 16) & 1u)) >> 16;   // RNE
    return (ushort)r;
}
__device__ __forceinline__ float bf2f(ushort u) {
    return __uint_as_float(((unsigned)u) << 16);
}

// ---------------- bf16 staging: one merged 384B-stride table ----------------
// row layout (ushort idx): [0..61]=xp, [62,63]=0, [64..137]=xf/xn interleaved, [138..191]=0
__global__ void cast_xall_kernel(const float* __restrict__ xp, const float* __restrict__ xf,
                                 const float* __restrict__ xn, ushort* __restrict__ xall) {
    int i = blockIdx.x * 256 + threadIdx.x;
    if (i >= N_NODES * 192) return;
    int node = i / 192, k = i - node * 192;
    float v = 0.f;
    if (k < 62) v = xp[node * 62 + k];
    else if (k >= 64 && k < 138) {
        int j = k - 64, d = j >> 1;
        v = (j & 1) ? xn[node * 37 + d] : xf[node * 37 + d];
    }
    xall[i] = f2bf(v);
}

// ---------------- CSR build ----------------
__global__ void zero_kernel(int* p, int n) {
    int i = blockIdx.x * blockDim.x + threadIdx.x;
    if (i < n) p[i] = 0;
}

__global__ void hist_kernel(const int* __restrict__ rows, int* __restrict__ counts) {
    int g = blockIdx.x * blockDim.x + threadIdx.x;
    if (g >= R_REL * E_NNZ) return;
    int r = g / E_NNZ;
    atomicAdd(&counts[r * N_NODES + rows[g]], 1);
}

__global__ void scan_part_kernel(const int* __restrict__ counts, int* __restrict__ bsum) {
    __shared__ int red[256];
    int base = blockIdx.x * 1024;
    int t = threadIdx.x;
    int s = 0;
    #pragma unroll
    for (int i = 0; i < 4; i++) {
        int idx = base + i * 256 + t;
        if (idx < RN_TOTAL) s += counts[idx];
    }
    red[t] = s; __syncthreads();
    for (int d = 128; d > 0; d >>= 1) {
        if (t < d) red[t] += red[t + d];
        __syncthreads();
    }
    if (t == 0) bsum[blockIdx.x] = red[0];
}

__global__ void scan_bsum_kernel(int* __restrict__ bsum, int* __restrict__ rp) {
    __shared__ int sh[256];
    int t = threadIdx.x;
    int v = (t < SCAN_BLK) ? bsum[t] : 0;
    sh[t] = v; __syncthreads();
    for (int d = 1; d < 256; d <<= 1) {
        int u = (t >= d) ? sh[t - d] : 0;
        __syncthreads();
        sh[t] += u;
        __syncthreads();
    }
    if (t < SCAN_BLK) bsum[t] = sh[t] - v;
    if (t == 255) rp[RN_TOTAL] = sh[255];
}

__global__ void scan_final_kernel(const int* __restrict__ counts, const int* __restrict__ bsum,
                                  int* __restrict__ rp, int* __restrict__ cursor) {
    __shared__ int sh[256];
    int base = blockIdx.x * 1024;
    int t = threadIdx.x;
    int c[4]; int s = 0;
    #pragma unroll
    for (int i = 0; i < 4; i++) {
        int idx = base + t * 4 + i;
        c[i] = (idx < RN_TOTAL) ? counts[idx] : 0;
        s += c[i];
    }
    sh[t] = s; __syncthreads();
    for (int d = 1; d < 256; d <<= 1) {
        int u = (t >= d) ? sh[t - d] : 0;
        __syncthreads();
        sh[t] += u;
        __syncthreads();
    }
    int off = bsum[blockIdx.x] + sh[t] - s;
    #pragma unroll
    for (int i = 0; i < 4; i++) {
        int idx = base + t * 4 + i;
        if (idx < RN_TOTAL) { rp[idx] = off; cursor[idx] = off; }
        off += c[i];
    }
}

__global__ void scatter_kernel(const int* __restrict__ rows, const int* __restrict__ cols,
                               const float* __restrict__ vals, int* __restrict__ cursor,
                               int2* __restrict__ cse) {
    int g = blockIdx.x * blockDim.x + threadIdx.x;
    if (g >= R_REL * E_NNZ) return;
    int r = g / E_NNZ;
    int p = atomicAdd(&cursor[r * N_NODES + rows[g]], 1);
    cse[p] = make_int2(cols[g], __float_as_int(vals[g]));
}

// ---------------- layer-1 spmm, all 3 views, merged table, x4 unroll -------
__global__ void spmm1_all_kernel(const ushort* __restrict__ xall,
                                 const int* __restrict__ rp, const int2* __restrict__ cse,
                                 float* __restrict__ Sp, float* __restrict__ Sf,
                                 float* __restrict__ Sn) {
    int wave = threadIdx.x >> 6, lane = threadIdx.x & 63;
    int row = blockIdx.x * 4 + wave;
    if (row >= N_NODES) return;
    bool lp = lane < 62, lf = lane < 37;
    int opx = lane;            // xp ushort offset (lanes 62,63 hit zero pad, in-row)
    int ofn = 64 + 2 * lane;   // xf/xn pair offset (lanes >=37 hit zero pad, in-row)
    for (int r = 0; r < R_REL; r++) {
        int e0 = rp[r * N_NODES + row], e1 = rp[r * N_NODES + row + 1];
        float ap = 0.f, af = 0.f, an = 0.f;
        int e = e0;
        for (; e + 4 <= e1; e += 4) {
            int2 q0 = cse[e], q1 = cse[e + 1], q2 = cse[e + 2], q3 = cse[e + 3];
            const ushort* b0 = xall + (size_t)q0.x * 192;
            const ushort* b1 = xall + (size_t)q1.x * 192;
            const ushort* b2 = xall + (size_t)q2.x * 192;
            const ushort* b3 = xall + (size_t)q3.x * 192;
            ushort  p0 = b0[opx], p1 = b1[opx], p2 = b2[opx], p3 = b3[opx];
            ushort2 u0 = *(const ushort2*)&b0[ofn];
            ushort2 u1 = *(const ushort2*)&b1[ofn];
            ushort2 u2 = *(const ushort2*)&b2[ofn];
            ushort2 u3 = *(const ushort2*)&b3[ofn];
            float v0 = __int_as_float(q0.y), v1 = __int_as_float(q1.y);
            float v2 = __int_as_float(q2.y), v3 = __int_as_float(q3.y);
            ap += v0 * bf2f(p0) + v1 * bf2f(p1) + v2 * bf2f(p2) + v3 * bf2f(p3);
            af += v0 * bf2f(u0.x) + v1 * bf2f(u1.x) + v2 * bf2f(u2.x) + v3 * bf2f(u3.x);
            an += v0 * bf2f(u0.y) + v1 * bf2f(u1.y) + v2 * bf2f(u2.y) + v3 * bf2f(u3.y);
        }
        for (; e < e1; e++) {
            int2 q = cse[e];
            const ushort* b = xall + (size_t)q.x * 192;
            float v = __int_as_float(q.y);
            ap += v * bf2f(b[opx]);
            ushort2 u = *(const ushort2*)&b[ofn];
            af += v * bf2f(u.x);
            an += v * bf2f(u.y);
        }
        if (lp) Sp[row * 248 + r * 62 + lane] = ap;
        if (lf) { Sf[row * 148 + r * 37 + lane] = af; Sn[row * 148 + r * 37 + lane] = an; }
    }
}

// ---------------- GEMM1: h = relu((x@Ws^T + sum_r S_r@Wr^T + btot)/5) ------
__launch_bounds__(256)
__global__ void gemm1_kernel(const float* __restrict__ x, const float* __restrict__ S,
                             const float* __restrict__ Ws, const float* __restrict__ bs,
                             const float* __restrict__ Wr, const float* __restrict__ br,
                             float* __restrict__ h, int din) {
    __shared__ float sA[64 * 63];
    __shared__ float sW[62 * 132];
    int t = threadIdx.x;
    int i0 = blockIdx.x * 64;
    int rg = t >> 5, cg = t & 31;
    float acc[8][4] = {};
    for (int s = 0; s < 5; s++) {
        const float* Aptr; int astride;
        if (s == 0) { Aptr = x; astride = din; }
        else        { Aptr = S + (s - 1) * din; astride = 4 * din; }
        const float* Wp = (s == 0) ? Ws : (Wr + (s - 1) * H_DIM * din);
        __syncthreads();
        for (int idx = t; idx < 64 * din; idx += 256) {
            int rr = idx / din, k = idx - rr * din;
            int grow = i0 + rr;
            sA[rr * 63 + k] = (grow < N_NODES) ? Aptr[grow * astride + k] : 0.f;
        }
        for (int idx = t; idx < H_DIM * din; idx += 256) {
            int j = idx / din, k = idx - j * din;
            sW[k * 132 + j] = Wp[j * din + k];
        }
        __syncthreads();
        for (int k = 0; k < din; k++) {
            float a[8];
            #pragma unroll
            for (int rr = 0; rr < 8; rr++) a[rr] = sA[(rg * 8 + rr) * 63 + k];
            float4 w = *(const float4*)&sW[k * 132 + cg * 4];
            #pragma unroll
            for (int rr = 0; rr < 8; rr++) {
                acc[rr][0] += a[rr] * w.x; acc[rr][1] += a[rr] * w.y;
                acc[rr][2] += a[rr] * w.z; acc[rr][3] += a[rr] * w.w;
            }
        }
    }
    int j0 = cg * 4;
    float btot[4];
    #pragma unroll
    for (int cc = 0; cc < 4; cc++) {
        float b = bs[j0 + cc];
        #pragma unroll
        for (int r = 0; r < R_REL; r++) b += br[r * H_DIM + j0 + cc];
        btot[cc] = b;
    }
    #pragma unroll
    for (int rr = 0; rr < 8; rr++) {
        int grow = i0 + rg * 8 + rr;
        if (grow < N_NODES) {
            float4 o;
            o.x = fmaxf((acc[rr][0] + btot[0]) * 0.2f, 0.f);
            o.y = fmaxf((acc[rr][1] + btot[1]) * 0.2f, 0.f);
            o.z = fmaxf((acc[rr][2] + btot[2]) * 0.2f, 0.f);
            o.w = fmaxf((acc[rr][3] + btot[3]) * 0.2f, 0.f);
            *(float4*)&h[grow * H_DIM + j0] = o;
        }
    }
}

// ---------------- GEMM2: Yself fp32 (ct=0), Yrel bf16 (ct=1..4) ------------
__launch_bounds__(256)
__global__ void gemm2_kernel(const float* __restrict__ h, const float* __restrict__ Ws2,
                             const float* __restrict__ Wr2, float* __restrict__ Yself,
                             ushort* __restrict__ Yrel) {
    __shared__ float sA[128 * 65];
    __shared__ float sW[64 * 68];
    int t = threadIdx.x;
    int i0 = blockIdx.x * 128;
    int ct = blockIdx.y;                     // 0..4 (0=self, 1..4=relations)
    int rg = t >> 4, cg = t & 15;
    const float* Wp = (ct == 0) ? Ws2 : (Wr2 + (ct - 1) * 64 * H_DIM);
    float acc[8][4] = {};
    for (int kc = 0; kc < 2; kc++) {
        __syncthreads();
        for (int idx = t; idx < 128 * 64; idx += 256) {
            int rr = idx >> 6, k = idx & 63;
            int grow = i0 + rr;
            sA[rr * 65 + k] = (grow < N_NODES) ? h[grow * H_DIM + kc * 64 + k] : 0.f;
        }
        for (int idx = t; idx < 64 * 64; idx += 256) {
            int j = idx >> 6, k = idx & 63;
            sW[k * 68 + j] = Wp[j * H_DIM + kc * 64 + k];
        }
        __syncthreads();
        for (int k = 0; k < 64; k++) {
            float a[8];
            #pragma unroll
            for (int rr = 0; rr < 8; rr++) a[rr] = sA[(rg * 8 + rr) * 65 + k];
            float4 w = *(const float4*)&sW[k * 68 + cg * 4];
            #pragma unroll
            for (int rr = 0; rr < 8; rr++) {
                acc[rr][0] += a[rr] * w.x; acc[rr][1] += a[rr] * w.y;
                acc[rr][2] += a[rr] * w.z; acc[rr][3] += a[rr] * w.w;
            }
        }
    }
    #pragma unroll
    for (int rr = 0; rr < 8; rr++) {
        int grow = i0 + rg * 8 + rr;
        if (grow < N_NODES) {
            if (ct == 0) {
                float4 o = make_float4(acc[rr][0], acc[rr][1], acc[rr][2], acc[rr][3]);
                *(float4*)&Yself[(size_t)grow * 64 + cg * 4] = o;
            } else {
                ushort4 o;
                o.x = f2bf(acc[rr][0]); o.y = f2bf(acc[rr][1]);
                o.z = f2bf(acc[rr][2]); o.w = f2bf(acc[rr][3]);
                *(ushort4*)&Yrel[(size_t)grow * 256 + (ct - 1) * 64 + cg * 4] = o;
            }
        }
    }
}

// ------- spmm2 (all 3 views) + bias + /5 + gated fusion, x4 unroll ---------
__global__ void spmm2z_all_kernel(const float* __restrict__ Ysp, const ushort* __restrict__ Yrp,
                                  const float* __restrict__ Ysf, const ushort* __restrict__ Yrf,
                                  const float* __restrict__ Ysn, const ushort* __restrict__ Yrn,
                                  const int* __restrict__ rp, const int2* __restrict__ cse,
                                  const float* __restrict__ p_bs, const float* __restrict__ p_br,
                                  const float* __restrict__ f_bs, const float* __restrict__ f_br,
                                  const float* __restrict__ n_bs, const float* __restrict__ n_br,
                                  const float* __restrict__ gW, const float* __restrict__ gb,
                                  float* __restrict__ z) {
    int wave = threadIdx.x >> 6, lane = threadIdx.x & 63;
    int row = blockIdx.x * 4 + wave;
    if (row >= N_NODES) return;
    float aP = Ysp[(size_t)row * 64 + lane] + p_bs[lane]
             + p_br[lane] + p_br[64 + lane] + p_br[128 + lane] + p_br[192 + lane];
    float aF = Ysf[(size_t)row * 64 + lane] + f_bs[lane]
             + f_br[lane] + f_br[64 + lane] + f_br[128 + lane] + f_br[192 + lane];
    float aN = Ysn[(size_t)row * 64 + lane] + n_bs[lane]
             + n_br[lane] + n_br[64 + lane] + n_br[128 + lane] + n_br[192 + lane];
    for (int r = 0; r < R_REL; r++) {
        int e0 = rp[r * N_NODES + row], e1 = rp[r * N_NODES + row + 1];
        const ushort* yp = Yrp + r * 64 + lane;
        const ushort* yf = Yrf + r * 64 + lane;
        const ushort* yn = Yrn + r * 64 + lane;
        int e = e0;
        for (; e + 4 <= e1; e += 4) {
            int2 q0 = cse[e], q1 = cse[e + 1], q2 = cse[e + 2], q3 = cse[e + 3];
            size_t o0 = (size_t)q0.x * 256, o1 = (size_t)q1.x * 256;
            size_t o2 = (size_t)q2.x * 256, o3 = (size_t)q3.x * 256;
            float pp0 = bf2f(yp[o0]), pp1 = bf2f(yp[o1]), pp2 = bf2f(yp[o2]), pp3 = bf2f(yp[o3]);
            float ff0 = bf2f(yf[o0]), ff1 = bf2f(yf[o1]), ff2 = bf2f(yf[o2]), ff3 = bf2f(yf[o3]);
            float nn0 = bf2f(yn[o0]), nn1 = bf2f(yn[o1]), nn2 = bf2f(yn[o2]), nn3 = bf2f(yn[o3]);
            float v0 = __int_as_float(q0.y), v1 = __int_as_float(q1.y);
            float v2 = __int_as_float(q2.y), v3 = __int_as_float(q3.y);
            aP += v0 * pp0 + v1 * pp1 + v2 * pp2 + v3 * pp3;
            aF += v0 * ff0 + v1 * ff1 + v2 * ff2 + v3 * ff3;
            aN += v0 * nn0 + v1 * nn1 + v2 * nn2 + v3 * nn3;
        }
        for (; e < e1; e++) {
            int2 q = cse[e];
            size_t o = (size_t)q.x * 256;
            float v = __int_as_float(q.y);
            aP += v * bf2f(yp[o]);
            aF += v * bf2f(yf[o]);
            aN += v * bf2f(yn[o]);
        }
    }
    aP *= 0.2f; aF *= 0.2f; aN *= 0.2f;
    float sp = aP * gW[lane], sf = aF * gW[64 + lane], sn = aN * gW[128 + lane];
    #pragma unroll
    for (int d = 32; d >= 1; d >>= 1) {
        sp += __shfl_xor(sp, d);
        sf += __shfl_xor(sf, d);
        sn += __shfl_xor(sn, d);
    }
    sp += gb[0]; sf += gb[1]; sn += gb[2];
    float m = fmaxf(sp, fmaxf(sf, sn));
    float ep = __expf(sp - m), ef = __expf(sf - m), en = __expf(sn - m);
    float inv = 1.f / (ep + ef + en);
    z[row * 64 + lane] = (ep * aP + ef * aF + en * aN) * inv;
}

// ---------------- edge decoder ----------------
__launch_bounds__(256)
__global__ void decoder_kernel(const float* __restrict__ z, const int* __restrict__ esrc,
                               const int* __restrict__ edst, const float* __restrict__ w1,
                               const float* __restrict__ b1, const float* __restrict__ w2,
                               const float* __restrict__ b2, float* __restrict__ out) {
    int e = blockIdx.x * blockDim.x + threadIdx.x;
    if (e >= ED_EDGES) return;
    const float* zs = z + (size_t)esrc[e] * 64;
    const float* zd = z + (size_t)edst[e] * 64;
    float hid[64];
    #pragma unroll
    for (int j = 0; j < 64; j++) hid[j] = b1[j];
    #pragma unroll 1
    for (int kc = 0; kc < 64; kc += 8) {
        float a[8], b[8], p[8], q[8];
        #pragma unroll
        for (int kk = 0; kk < 8; kk++) {
            a[kk] = zs[kc + kk]; b[kk] = zd[kc + kk];
            p[kk] = a[kk] * b[kk]; q[kk] = fabsf(a[kk] - b[kk]);
        }
        #pragma unroll
        for (int j = 0; j < 64; j++) {
            const float* wrow = w1 + j * 256 + kc;
            float s = hid[j];
            #pragma unroll
            for (int kk = 0; kk < 8; kk++) {
                s += a[kk] * wrow[kk] + b[kk] * wrow[64 + kk]
                   + p[kk] * wrow[128 + kk] + q[kk] * wrow[192 + kk];
            }
            hid[j] = s;
        }
    }
    float logit = b2[0];
    #pragma unroll
    for (int j = 0; j < 64; j++) logit += fmaxf(hid[j], 0.f) * w2[j];
    out[e] = logit;
}

// ---------------- host ----------------
extern "C" void kernel_launch(void* const* d_in, const int* in_sizes, int n_in,
                              void* d_out, int out_size, void* d_ws, size_t ws_size,
                              hipStream_t stream) {
    const float* x_p = (const float*)d_in[0];
    const float* x_f = (const float*)d_in[1];
    const float* x_n = (const float*)d_in[2];
    const float* p1_Ws = (const float*)d_in[3];  const float* p1_bs = (const float*)d_in[4];
    const float* p1_Wr = (const float*)d_in[5];  const float* p1_br = (const float*)d_in[6];
    const float* p2_Ws = (const float*)d_in[7];  const float* p2_bs = (const float*)d_in[8];
    const float* p2_Wr = (const float*)d_in[9];  const float* p2_br = (const float*)d_in[10];
    const float* f1_Ws = (const float*)d_in[11]; const float* f1_bs = (const float*)d_in[12];
    const float* f1_Wr = (const float*)d_in[13]; const float* f1_br = (const float*)d_in[14];
    const float* f2_Ws = (const float*)d_in[15]; const float* f2_bs = (const float*)d_in[16];
    const float* f2_Wr = (const float*)d_in[17]; const float* f2_br = (const float*)d_in[18];
    const float* n1_Ws = (const float*)d_in[19]; const float* n1_bs = (const float*)d_in[20];
    const float* n1_Wr = (const float*)d_in[21]; const float* n1_br = (const float*)d_in[22];
    const float* n2_Ws = (const float*)d_in[23]; const float* n2_bs = (const float*)d_in[24];
    const float* n2_Wr = (const float*)d_in[25]; const float* n2_br = (const float*)d_in[26];
    const float* gate_W = (const float*)d_in[27]; const float* gate_b = (const float*)d_in[28];
    const float* dec_W1 = (const float*)d_in[29]; const float* dec_b1 = (const float*)d_in[30];
    const float* dec_W2 = (const float*)d_in[31]; const float* dec_b2 = (const float*)d_in[32];
    const int*   adj_rows = (const int*)d_in[33];
    const int*   adj_cols = (const int*)d_in[34];
    const float* adj_vals = (const float*)d_in[35];
    const int*   edge_src = (const int*)d_in[36];
    const int*   edge_dst = (const int*)d_in[37];

    char* ws = (char*)d_ws;
    int*    rp      = (int*)(ws + WS_RP);
    int*    cursor  = (int*)(ws + WS_CUR);
    int*    counts  = (int*)(ws + WS_CNT);
    int*    bsum    = (int*)(ws + WS_BSUM);
    int2*   cse     = (int2*)(ws + WS_CV);
    ushort* xall    = (ushort*)(ws + WS_XALL);
    float*  S_p = (float*)(ws + WS_SP);
    float*  S_f = (float*)(ws + WS_SF);
    float*  S_n = (float*)(ws + WS_SN);
    float*  h_p = (float*)(ws + WS_HP);
    float*  h_f = (float*)(ws + WS_HF);
    float*  h_n = (float*)(ws + WS_HN);
    float*  Ys_p = (float*)(ws + WS_YSP);  ushort* Yr_p = (ushort*)(ws + WS_YRP);
    float*  Ys_f = (float*)(ws + WS_YSF);  ushort* Yr_f = (ushort*)(ws + WS_YRF);
    float*  Ys_n = (float*)(ws + WS_YSN);  ushort* Yr_n = (ushort*)(ws + WS_YRN);
    float*  z   = (float*)(ws + WS_Z);
    float*  out = (float*)d_out;

    // bf16 staging of node features (merged, 384B-stride, zero-padded)
    cast_xall_kernel<<<(N_NODES * 192 + 255) / 256, 256, 0, stream>>>(x_p, x_f, x_n, xall);

    // CSR build (shared across views/layers)
    zero_kernel<<<(RN_TOTAL + 255) / 256, 256, 0, stream>>>(counts, RN_TOTAL);
    hist_kernel<<<(R_REL * E_NNZ + 255) / 256, 256, 0, stream>>>(adj_rows, counts);
    scan_part_kernel<<<SCAN_BLK, 256, 0, stream>>>(counts, bsum);
    scan_bsum_kernel<<<1, 256, 0, stream>>>(bsum, rp);
    scan_final_kernel<<<SCAN_BLK, 256, 0, stream>>>(counts, bsum, rp, cursor);
    scatter_kernel<<<(R_REL * E_NNZ + 255) / 256, 256, 0, stream>>>(
        adj_rows, adj_cols, adj_vals, cursor, cse);

    // layer-1 spmm for all 3 views
    spmm1_all_kernel<<<N_NODES / 4, 256, 0, stream>>>(xall, rp, cse, S_p, S_f, S_n);

    // layer-1 GEMMs -> h_v (fp32)
    int g1 = (N_NODES + 63) / 64;
    gemm1_kernel<<<g1, 256, 0, stream>>>(x_p, S_p, p1_Ws, p1_bs, p1_Wr, p1_br, h_p, 62);
    gemm1_kernel<<<g1, 256, 0, stream>>>(x_f, S_f, f1_Ws, f1_bs, f1_Wr, f1_br, h_f, 37);
    gemm1_kernel<<<g1, 256, 0, stream>>>(x_n, S_n, n1_Ws, n1_bs, n1_Wr, n1_br, h_n, 37);

    // layer-2 GEMMs (matmul-first): Yself fp32 + Yrel bf16 per view
    dim3 g2((N_NODES + 127) / 128, 5);
    gemm2_kernel<<<g2, 256, 0, stream>>>(h_p, p2_Ws, p2_Wr, Ys_p, Yr_p);
    gemm2_kernel<<<g2, 256, 0, stream>>>(h_f, f2_Ws, f2_Wr, Ys_f, Yr_f);
    gemm2_kernel<<<g2, 256, 0, stream>>>(h_n, n2_Ws, n2_Wr, Ys_n, Yr_n);

    // spmm2 (all views) + bias + gated fusion -> z
    spmm2z_all_kernel<<<N_NODES / 4, 256, 0, stream>>>(
        Ys_p, Yr_p, Ys_f, Yr_f, Ys_n, Yr_n, rp, cse,
        p2_bs, p2_br, f2_bs, f2_br, n2_bs, n2_br, gate_W, gate_b, z);

    // edge decoder -> logits
    decoder_kernel<<<(ED_EDGES + 255) / 256, 256, 0, stream>>>(
        z, edge_src, edge_dst, dec_W1, dec_b1, dec_W2, dec_b2, out);
}

// Round 5
// 1428.696 us; speedup vs baseline: 2.3783x; 1.1788x over previous
//
#include <hip/hip_runtime.h>

#define N_NODES 50000
#define R_REL   4
#define E_NNZ   800000
#define ED_EDGES 200000
#define H_DIM   128
#define L_DIM   64

#define RN_TOTAL (R_REL * N_NODES)    // 200000
#define ETOT     (R_REL * E_NNZ)      // 3,200,000

// ----- radix CSR-build constants -----
#define EPB   8192                    // edges per radix block
#define NB    391                     // ceil(ETOT/EPB)
#define RBK   196                     // row buckets per relation (256 rows each)
#define KBK   (R_REL * RBK)           // 784 total buckets
#define HTOT  (KBK * NB)              // 306,544 histogram entries
#define SCB   300                     // ceil(HTOT/1024) scan blocks
#define MAXB  6144                    // LDS edge capacity per bucket (mean 4096, +32 sigma)

// ---------------- workspace layout (bytes); budget <= 213,601,536 ----------
#define WS_RP    0u            // (RN+1) int -> 800,256
#define WS_HIST  800256u       // HTOT int = 1,226,176 -> 2,026,496 (pad)
#define WS_BSUM  2026496u      // 1024 int -> 2,030,592
#define WS_CV    2030592u      // ETOT int2 = 25.6e6 -> 27,630,592   (final cse, persistent)
#define WS_TMP   27630720u     // ETOT int2 = 25.6e6 -> 53,230,720   (bucketed tmp; later h_n)
#define WS_XALL  53230720u     // N*192 ushort = 19.2e6 -> 72,430,720 (later Ys_p)
#define WS_SP    72430720u     // N*248 f32 = 49.6e6 -> 122,030,720  (later h_f, Ys_f)
#define WS_SF    122030720u    // N*148 f32 = 29.6e6 -> 151,630,720  (later Yr_p)
#define WS_SN    151630720u    // N*148 f32 = 29.6e6 -> 181,230,720  (later Yr_f)
#define WS_HPR   181230720u    // N*128 f32 = 25.6e6 -> 206,830,720  (h_p; later Ys_n, z)
#define WS_HN    WS_TMP                    // h_n reuses tmp (dead after bucket_sort)
#define WS_HF    WS_SP                     // h_f reuses S_p (dead after gemm1_p)
#define WS_YSP   WS_XALL                   // 12.8e6 (xall dead after spmm1)
#define WS_YSF   (WS_SP + 25600000u)       // 98,030,720 (S_p tail)
#define WS_YRP   WS_SF                     // 25.6e6 (S_f dead after gemm1_f)
#define WS_YRF   WS_SN                     // 25.6e6 (S_n dead after gemm1_n)
#define WS_YSN   WS_HPR                    // 12.8e6 (h_p dead after gemm2_p)
#define WS_YRN   WS_HF                     // 25.6e6 (h_f dead after gemm2_f)
#define WS_Z     194030720u                // 12.8e6 -> 206,830,720 (h_p tail)

__device__ __forceinline__ ushort f2bf(float f) {
    unsigned u = __float_as_uint(f);
    unsigned r = (u + 0x7fffu + ((u >> 16) & 1u)) >> 16;   // RNE
    return (ushort)r;
}
__device__ __forceinline__ float bf2f(ushort u) {
    return __uint_as_float(((unsigned)u) << 16);
}

// ---------------- bf16 staging: one merged 384B-stride table ----------------
// row layout (ushort idx): [0..61]=xp, [62,63]=0, [64..137]=xf/xn interleaved, [138..191]=0
__global__ void cast_xall_kernel(const float* __restrict__ xp, const float* __restrict__ xf,
                                 const float* __restrict__ xn, ushort* __restrict__ xall) {
    int i = blockIdx.x * 256 + threadIdx.x;
    if (i >= N_NODES * 192) return;
    int node = i / 192, k = i - node * 192;
    float v = 0.f;
    if (k < 62) v = xp[node * 62 + k];
    else if (k >= 64 && k < 138) {
        int j = k - 64, d = j >> 1;
        v = (j & 1) ? xn[node * 37 + d] : xf[node * 37 + d];
    }
    xall[i] = f2bf(v);
}

// ---------------- radix CSR build ----------------
// Pass A: per-block histogram over KBK buckets, bucket-major layout H[bucket*NB+blk]
__global__ void radix_hist_kernel(const int* __restrict__ rows, int* __restrict__ H) {
    __shared__ int hist[KBK];
    int blk = blockIdx.x, t = threadIdx.x;
    for (int i = t; i < KBK; i += 256) hist[i] = 0;
    __syncthreads();
    int base = blk * EPB;
    #pragma unroll 1
    for (int i = 0; i < EPB / 256; i++) {
        int g = base + i * 256 + t;
        if (g < ETOT) {
            int r = g / E_NNZ;
            atomicAdd(&hist[r * RBK + (rows[g] >> 8)], 1);
        }
    }
    __syncthreads();
    for (int i = t; i < KBK; i += 256) H[i * NB + blk] = hist[i];
}

// 3-phase scan over H[HTOT] (in place: counts -> exclusive positions)
__global__ void scan_part_kernel(const int* __restrict__ H, int* __restrict__ bsum) {
    __shared__ int red[256];
    int base = blockIdx.x * 1024, t = threadIdx.x;
    int s = 0;
    #pragma unroll
    for (int i = 0; i < 4; i++) {
        int idx = base + i * 256 + t;
        if (idx < HTOT) s += H[idx];
    }
    red[t] = s; __syncthreads();
    for (int d = 128; d > 0; d >>= 1) {
        if (t < d) red[t] += red[t + d];
        __syncthreads();
    }
    if (t == 0) bsum[blockIdx.x] = red[0];
}

__global__ void scan_bsum_kernel(int* __restrict__ bsum, int* __restrict__ rp) {
    __shared__ int sh[512];
    int t = threadIdx.x;
    int v = (t < SCB) ? bsum[t] : 0;
    sh[t] = v; __syncthreads();
    for (int d = 1; d < 512; d <<= 1) {
        int u = (t >= d) ? sh[t - d] : 0;
        __syncthreads();
        sh[t] += u;
        __syncthreads();
    }
    if (t < SCB) bsum[t] = sh[t] - v;
    if (t == 0) rp[RN_TOTAL] = ETOT;
}

__global__ void scan_final_kernel(int* __restrict__ H, const int* __restrict__ bsum) {
    __shared__ int sh[256];
    int base = blockIdx.x * 1024, t = threadIdx.x;
    int c[4]; int s = 0;
    #pragma unroll
    for (int i = 0; i < 4; i++) {
        int idx = base + t * 4 + i;
        c[i] = (idx < HTOT) ? H[idx] : 0;
        s += c[i];
    }
    sh[t] = s; __syncthreads();
    for (int d = 1; d < 256; d <<= 1) {
        int u = (t >= d) ? sh[t - d] : 0;
        __syncthreads();
        sh[t] += u;
        __syncthreads();
    }
    int off = bsum[blockIdx.x] + sh[t] - s;
    #pragma unroll
    for (int i = 0; i < 4; i++) {
        int idx = base + t * 4 + i;
        if (idx < HTOT) H[idx] = off;
        off += c[i];
    }
}

// Pass B: scatter edges into block-private bucket sub-ranges (coalesced-ish)
// tmp payload: (col | rowlow<<16, val-bits)
__global__ void radix_scatter_kernel(const int* __restrict__ rows, const int* __restrict__ cols,
                                     const float* __restrict__ vals, const int* __restrict__ H,
                                     int2* __restrict__ tmp) {
    __shared__ int cur[KBK];
    int blk = blockIdx.x, t = threadIdx.x;
    for (int i = t; i < KBK; i += 256) cur[i] = H[i * NB + blk];
    __syncthreads();
    int base = blk * EPB;
    #pragma unroll 1
    for (int i = 0; i < EPB / 256; i++) {
        int g = base + i * 256 + t;
        if (g < ETOT) {
            int r = g / E_NNZ;
            int row = rows[g];
            int b = r * RBK + (row >> 8);
            int p = atomicAdd(&cur[b], 1);
            tmp[p] = make_int2(cols[g] | ((row & 255) << 16), __float_as_int(vals[g]));
        }
    }
}

// Stage 2: per-bucket LDS counting sort by rowlow -> final cse + rp
__launch_bounds__(256)
__global__ void bucket_sort_kernel(const int2* __restrict__ tmp, const int* __restrict__ H,
                                   int* __restrict__ rp, int2* __restrict__ cse) {
    __shared__ int hist[256];
    __shared__ int sc[256];
    __shared__ int cur[256];
    __shared__ int2 eb[MAXB];     // 48 KiB
    int b = blockIdx.x, t = threadIdx.x;
    int start = H[b * NB];
    int end = (b == KBK - 1) ? ETOT : H[(b + 1) * NB];
    int cnt = end - start;
    bool useLds = (cnt <= MAXB);
    hist[t] = 0;
    __syncthreads();
    for (int i = t; i < cnt; i += 256) {
        int2 e = tmp[start + i];
        if (useLds) eb[i] = e;
        atomicAdd(&hist[(e.x >> 16) & 255], 1);
    }
    __syncthreads();
    // exclusive scan of hist
    sc[t] = hist[t]; __syncthreads();
    for (int d = 1; d < 256; d <<= 1) {
        int v = (t >= d) ? sc[t - d] : 0;
        __syncthreads();
        sc[t] += v;
        __syncthreads();
    }
    int pref = sc[t] - hist[t];   // exclusive
    // rp for this bucket's rows
    int r = b / RBK, rh = b - r * RBK;
    int grow = rh * 256 + t;
    if (grow < N_NODES) rp[r * N_NODES + grow] = start + pref;
    cur[t] = start + pref;
    __syncthreads();
    // scatter to final positions
    for (int i = t; i < cnt; i += 256) {
        int2 e = useLds ? eb[i] : tmp[start + i];
        int rl = (e.x >> 16) & 255;
        int p = atomicAdd(&cur[rl], 1);
        cse[p] = make_int2(e.x & 0xFFFF, e.y);
    }
}

// ---------------- layer-1 spmm, all 3 views, merged table, x4 unroll -------
__global__ void spmm1_all_kernel(const ushort* __restrict__ xall,
                                 const int* __restrict__ rp, const int2* __restrict__ cse,
                                 float* __restrict__ Sp, float* __restrict__ Sf,
                                 float* __restrict__ Sn) {
    int wave = threadIdx.x >> 6, lane = threadIdx.x & 63;
    int row = blockIdx.x * 4 + wave;
    if (row >= N_NODES) return;
    bool lp = lane < 62, lf = lane < 37;
    int opx = lane;            // xp ushort offset (lanes 62,63 hit zero pad, in-row)
    int ofn = 64 + 2 * lane;   // xf/xn pair offset (lanes >=37 hit zero pad, in-row)
    for (int r = 0; r < R_REL; r++) {
        int e0 = rp[r * N_NODES + row], e1 = rp[r * N_NODES + row + 1];
        float ap = 0.f, af = 0.f, an = 0.f;
        int e = e0;
        for (; e + 4 <= e1; e += 4) {
            int2 q0 = cse[e], q1 = cse[e + 1], q2 = cse[e + 2], q3 = cse[e + 3];
            const ushort* b0 = xall + (size_t)q0.x * 192;
            const ushort* b1 = xall + (size_t)q1.x * 192;
            const ushort* b2 = xall + (size_t)q2.x * 192;
            const ushort* b3 = xall + (size_t)q3.x * 192;
            ushort  p0 = b0[opx], p1 = b1[opx], p2 = b2[opx], p3 = b3[opx];
            ushort2 u0 = *(const ushort2*)&b0[ofn];
            ushort2 u1 = *(const ushort2*)&b1[ofn];
            ushort2 u2 = *(const ushort2*)&b2[ofn];
            ushort2 u3 = *(const ushort2*)&b3[ofn];
            float v0 = __int_as_float(q0.y), v1 = __int_as_float(q1.y);
            float v2 = __int_as_float(q2.y), v3 = __int_as_float(q3.y);
            ap += v0 * bf2f(p0) + v1 * bf2f(p1) + v2 * bf2f(p2) + v3 * bf2f(p3);
            af += v0 * bf2f(u0.x) + v1 * bf2f(u1.x) + v2 * bf2f(u2.x) + v3 * bf2f(u3.x);
            an += v0 * bf2f(u0.y) + v1 * bf2f(u1.y) + v2 * bf2f(u2.y) + v3 * bf2f(u3.y);
        }
        for (; e < e1; e++) {
            int2 q = cse[e];
            const ushort* b = xall + (size_t)q.x * 192;
            float v = __int_as_float(q.y);
            ap += v * bf2f(b[opx]);
            ushort2 u = *(const ushort2*)&b[ofn];
            af += v * bf2f(u.x);
            an += v * bf2f(u.y);
        }
        if (lp) Sp[row * 248 + r * 62 + lane] = ap;
        if (lf) { Sf[row * 148 + r * 37 + lane] = af; Sn[row * 148 + r * 37 + lane] = an; }
    }
}

// ---------------- GEMM1: h = relu((x@Ws^T + sum_r S_r@Wr^T + btot)/5) ------
__launch_bounds__(256)
__global__ void gemm1_kernel(const float* __restrict__ x, const float* __restrict__ S,
                             const float* __restrict__ Ws, const float* __restrict__ bs,
                             const float* __restrict__ Wr, const float* __restrict__ br,
                             float* __restrict__ h, int din) {
    __shared__ float sA[64 * 63];
    __shared__ float sW[62 * 132];
    int t = threadIdx.x;
    int i0 = blockIdx.x * 64;
    int rg = t >> 5, cg = t & 31;
    float acc[8][4] = {};
    for (int s = 0; s < 5; s++) {
        const float* Aptr; int astride;
        if (s == 0) { Aptr = x; astride = din; }
        else        { Aptr = S + (s - 1) * din; astride = 4 * din; }
        const float* Wp = (s == 0) ? Ws : (Wr + (s - 1) * H_DIM * din);
        __syncthreads();
        for (int idx = t; idx < 64 * din; idx += 256) {
            int rr = idx / din, k = idx - rr * din;
            int grow = i0 + rr;
            sA[rr * 63 + k] = (grow < N_NODES) ? Aptr[grow * astride + k] : 0.f;
        }
        for (int idx = t; idx < H_DIM * din; idx += 256) {
            int j = idx / din, k = idx - j * din;
            sW[k * 132 + j] = Wp[j * din + k];
        }
        __syncthreads();
        for (int k = 0; k < din; k++) {
            float a[8];
            #pragma unroll
            for (int rr = 0; rr < 8; rr++) a[rr] = sA[(rg * 8 + rr) * 63 + k];
            float4 w = *(const float4*)&sW[k * 132 + cg * 4];
            #pragma unroll
            for (int rr = 0; rr < 8; rr++) {
                acc[rr][0] += a[rr] * w.x; acc[rr][1] += a[rr] * w.y;
                acc[rr][2] += a[rr] * w.z; acc[rr][3] += a[rr] * w.w;
            }
        }
    }
    int j0 = cg * 4;
    float btot[4];
    #pragma unroll
    for (int cc = 0; cc < 4; cc++) {
        float b = bs[j0 + cc];
        #pragma unroll
        for (int r = 0; r < R_REL; r++) b += br[r * H_DIM + j0 + cc];
        btot[cc] = b;
    }
    #pragma unroll
    for (int rr = 0; rr < 8; rr++) {
        int grow = i0 + rg * 8 + rr;
        if (grow < N_NODES) {
            float4 o;
            o.x = fmaxf((acc[rr][0] + btot[0]) * 0.2f, 0.f);
            o.y = fmaxf((acc[rr][1] + btot[1]) * 0.2f, 0.f);
            o.z = fmaxf((acc[rr][2] + btot[2]) * 0.2f, 0.f);
            o.w = fmaxf((acc[rr][3] + btot[3]) * 0.2f, 0.f);
            *(float4*)&h[grow * H_DIM + j0] = o;
        }
    }
}

// ---------------- GEMM2: Yself fp32 (ct=0), Yrel bf16 (ct=1..4) ------------
__launch_bounds__(256)
__global__ void gemm2_kernel(const float* __restrict__ h, const float* __restrict__ Ws2,
                             const float* __restrict__ Wr2, float* __restrict__ Yself,
                             ushort* __restrict__ Yrel) {
    __shared__ float sA[128 * 65];
    __shared__ float sW[64 * 68];
    int t = threadIdx.x;
    int i0 = blockIdx.x * 128;
    int ct = blockIdx.y;                     // 0..4 (0=self, 1..4=relations)
    int rg = t >> 4, cg = t & 15;
    const float* Wp = (ct == 0) ? Ws2 : (Wr2 + (ct - 1) * 64 * H_DIM);
    float acc[8][4] = {};
    for (int kc = 0; kc < 2; kc++) {
        __syncthreads();
        for (int idx = t; idx < 128 * 64; idx += 256) {
            int rr = idx >> 6, k = idx & 63;
            int grow = i0 + rr;
            sA[rr * 65 + k] = (grow < N_NODES) ? h[grow * H_DIM + kc * 64 + k] : 0.f;
        }
        for (int idx = t; idx < 64 * 64; idx += 256) {
            int j = idx >> 6, k = idx & 63;
            sW[k * 68 + j] = Wp[j * H_DIM + kc * 64 + k];
        }
        __syncthreads();
        for (int k = 0; k < 64; k++) {
            float a[8];
            #pragma unroll
            for (int rr = 0; rr < 8; rr++) a[rr] = sA[(rg * 8 + rr) * 65 + k];
            float4 w = *(const float4*)&sW[k * 68 + cg * 4];
            #pragma unroll
            for (int rr = 0; rr < 8; rr++) {
                acc[rr][0] += a[rr] * w.x; acc[rr][1] += a[rr] * w.y;
                acc[rr][2] += a[rr] * w.z; acc[rr][3] += a[rr] * w.w;
            }
        }
    }
    #pragma unroll
    for (int rr = 0; rr < 8; rr++) {
        int grow = i0 + rg * 8 + rr;
        if (grow < N_NODES) {
            if (ct == 0) {
                float4 o = make_float4(acc[rr][0], acc[rr][1], acc[rr][2], acc[rr][3]);
                *(float4*)&Yself[(size_t)grow * 64 + cg * 4] = o;
            } else {
                ushort4 o;
                o.x = f2bf(acc[rr][0]); o.y = f2bf(acc[rr][1]);
                o.z = f2bf(acc[rr][2]); o.w = f2bf(acc[rr][3]);
                *(ushort4*)&Yrel[(size_t)grow * 256 + (ct - 1) * 64 + cg * 4] = o;
            }
        }
    }
}

// ------- spmm2 (all 3 views) + bias + /5 + gated fusion, x4 unroll ---------
__global__ void spmm2z_all_kernel(const float* __restrict__ Ysp, const ushort* __restrict__ Yrp,
                                  const float* __restrict__ Ysf, const ushort* __restrict__ Yrf,
                                  const float* __restrict__ Ysn, const ushort* __restrict__ Yrn,
                                  const int* __restrict__ rp, const int2* __restrict__ cse,
                                  const float* __restrict__ p_bs, const float* __restrict__ p_br,
                                  const float* __restrict__ f_bs, const float* __restrict__ f_br,
                                  const float* __restrict__ n_bs, const float* __restrict__ n_br,
                                  const float* __restrict__ gW, const float* __restrict__ gb,
                                  float* __restrict__ z) {
    int wave = threadIdx.x >> 6, lane = threadIdx.x & 63;
    int row = blockIdx.x * 4 + wave;
    if (row >= N_NODES) return;
    float aP = Ysp[(size_t)row * 64 + lane] + p_bs[lane]
             + p_br[lane] + p_br[64 + lane] + p_br[128 + lane] + p_br[192 + lane];
    float aF = Ysf[(size_t)row * 64 + lane] + f_bs[lane]
             + f_br[lane] + f_br[64 + lane] + f_br[128 + lane] + f_br[192 + lane];
    float aN = Ysn[(size_t)row * 64 + lane] + n_bs[lane]
             + n_br[lane] + n_br[64 + lane] + n_br[128 + lane] + n_br[192 + lane];
    for (int r = 0; r < R_REL; r++) {
        int e0 = rp[r * N_NODES + row], e1 = rp[r * N_NODES + row + 1];
        const ushort* yp = Yrp + r * 64 + lane;
        const ushort* yf = Yrf + r * 64 + lane;
        const ushort* yn = Yrn + r * 64 + lane;
        int e = e0;
        for (; e + 4 <= e1; e += 4) {
            int2 q0 = cse[e], q1 = cse[e + 1], q2 = cse[e + 2], q3 = cse[e + 3];
            size_t o0 = (size_t)q0.x * 256, o1 = (size_t)q1.x * 256;
            size_t o2 = (size_t)q2.x * 256, o3 = (size_t)q3.x * 256;
            float pp0 = bf2f(yp[o0]), pp1 = bf2f(yp[o1]), pp2 = bf2f(yp[o2]), pp3 = bf2f(yp[o3]);
            float ff0 = bf2f(yf[o0]), ff1 = bf2f(yf[o1]), ff2 = bf2f(yf[o2]), ff3 = bf2f(yf[o3]);
            float nn0 = bf2f(yn[o0]), nn1 = bf2f(yn[o1]), nn2 = bf2f(yn[o2]), nn3 = bf2f(yn[o3]);
            float v0 = __int_as_float(q0.y), v1 = __int_as_float(q1.y);
            float v2 = __int_as_float(q2.y), v3 = __int_as_float(q3.y);
            aP += v0 * pp0 + v1 * pp1 + v2 * pp2 + v3 * pp3;
            aF += v0 * ff0 + v1 * ff1 + v2 * ff2 + v3 * ff3;
            aN += v0 * nn0 + v1 * nn1 + v2 * nn2 + v3 * nn3;
        }
        for (; e < e1; e++) {
            int2 q = cse[e];
            size_t o = (size_t)q.x * 256;
            float v = __int_as_float(q.y);
            aP += v * bf2f(yp[o]);
            aF += v * bf2f(yf[o]);
            aN += v * bf2f(yn[o]);
        }
    }
    aP *= 0.2f; aF *= 0.2f; aN *= 0.2f;
    float sp = aP * gW[lane], sf = aF * gW[64 + lane], sn = aN * gW[128 + lane];
    #pragma unroll
    for (int d = 32; d >= 1; d >>= 1) {
        sp += __shfl_xor(sp, d);
        sf += __shfl_xor(sf, d);
        sn += __shfl_xor(sn, d);
    }
    sp += gb[0]; sf += gb[1]; sn += gb[2];
    float m = fmaxf(sp, fmaxf(sf, sn));
    float ep = __expf(sp - m), ef = __expf(sf - m), en = __expf(sn - m);
    float inv = 1.f / (ep + ef + en);
    z[row * 64 + lane] = (ep * aP + ef * aF + en * aN) * inv;
}

// ---------------- edge decoder ----------------
__launch_bounds__(256)
__global__ void decoder_kernel(const float* __restrict__ z, const int* __restrict__ esrc,
                               const int* __restrict__ edst, const float* __restrict__ w1,
                               const float* __restrict__ b1, const float* __restrict__ w2,
                               const float* __restrict__ b2, float* __restrict__ out) {
    int e = blockIdx.x * blockDim.x + threadIdx.x;
    if (e >= ED_EDGES) return;
    const float* zs = z + (size_t)esrc[e] * 64;
    const float* zd = z + (size_t)edst[e] * 64;
    float hid[64];
    #pragma unroll
    for (int j = 0; j < 64; j++) hid[j] = b1[j];
    #pragma unroll 1
    for (int kc = 0; kc < 64; kc += 8) {
        float a[8], b[8], p[8], q[8];
        #pragma unroll
        for (int kk = 0; kk < 8; kk++) {
            a[kk] = zs[kc + kk]; b[kk] = zd[kc + kk];
            p[kk] = a[kk] * b[kk]; q[kk] = fabsf(a[kk] - b[kk]);
        }
        #pragma unroll
        for (int j = 0; j < 64; j++) {
            const float* wrow = w1 + j * 256 + kc;
            float s = hid[j];
            #pragma unroll
            for (int kk = 0; kk < 8; kk++) {
                s += a[kk] * wrow[kk] + b[kk] * wrow[64 + kk]
                   + p[kk] * wrow[128 + kk] + q[kk] * wrow[192 + kk];
            }
            hid[j] = s;
        }
    }
    float logit = b2[0];
    #pragma unroll
    for (int j = 0; j < 64; j++) logit += fmaxf(hid[j], 0.f) * w2[j];
    out[e] = logit;
}

// ---------------- host ----------------
extern "C" void kernel_launch(void* const* d_in, const int* in_sizes, int n_in,
                              void* d_out, int out_size, void* d_ws, size_t ws_size,
                              hipStream_t stream) {
    const float* x_p = (const float*)d_in[0];
    const float* x_f = (const float*)d_in[1];
    const float* x_n = (const float*)d_in[2];
    const float* p1_Ws = (const float*)d_in[3];  const float* p1_bs = (const float*)d_in[4];
    const float* p1_Wr = (const float*)d_in[5];  const float* p1_br = (const float*)d_in[6];
    const float* p2_Ws = (const float*)d_in[7];  const float* p2_bs = (const float*)d_in[8];
    const float* p2_Wr = (const float*)d_in[9];  const float* p2_br = (const float*)d_in[10];
    const float* f1_Ws = (const float*)d_in[11]; const float* f1_bs = (const float*)d_in[12];
    const float* f1_Wr = (const float*)d_in[13]; const float* f1_br = (const float*)d_in[14];
    const float* f2_Ws = (const float*)d_in[15]; const float* f2_bs = (const float*)d_in[16];
    const float* f2_Wr = (const float*)d_in[17]; const float* f2_br = (const float*)d_in[18];
    const float* n1_Ws = (const float*)d_in[19]; const float* n1_bs = (const float*)d_in[20];
    const float* n1_Wr = (const float*)d_in[21]; const float* n1_br = (const float*)d_in[22];
    const float* n2_Ws = (const float*)d_in[23]; const float* n2_bs = (const float*)d_in[24];
    const float* n2_Wr = (const float*)d_in[25]; const float* n2_br = (const float*)d_in[26];
    const float* gate_W = (const float*)d_in[27]; const float* gate_b = (const float*)d_in[28];
    const float* dec_W1 = (const float*)d_in[29]; const float* dec_b1 = (const float*)d_in[30];
    const float* dec_W2 = (const float*)d_in[31]; const float* dec_b2 = (const float*)d_in[32];
    const int*   adj_rows = (const int*)d_in[33];
    const int*   adj_cols = (const int*)d_in[34];
    const float* adj_vals = (const float*)d_in[35];
    const int*   edge_src = (const int*)d_in[36];
    const int*   edge_dst = (const int*)d_in[37];

    char* ws = (char*)d_ws;
    int*    rp   = (int*)(ws + WS_RP);
    int*    H    = (int*)(ws + WS_HIST);
    int*    bsum = (int*)(ws + WS_BSUM);
    int2*   cse  = (int2*)(ws + WS_CV);
    int2*   tmp  = (int2*)(ws + WS_TMP);
    ushort* xall = (ushort*)(ws + WS_XALL);
    float*  S_p = (float*)(ws + WS_SP);
    float*  S_f = (float*)(ws + WS_SF);
    float*  S_n = (float*)(ws + WS_SN);
    float*  h_p = (float*)(ws + WS_HPR);
    float*  h_f = (float*)(ws + WS_HF);
    float*  h_n = (float*)(ws + WS_HN);
    float*  Ys_p = (float*)(ws + WS_YSP);  ushort* Yr_p = (ushort*)(ws + WS_YRP);
    float*  Ys_f = (float*)(ws + WS_YSF);  ushort* Yr_f = (ushort*)(ws + WS_YRF);
    float*  Ys_n = (float*)(ws + WS_YSN);  ushort* Yr_n = (ushort*)(ws + WS_YRN);
    float*  z   = (float*)(ws + WS_Z);
    float*  out = (float*)d_out;

    // bf16 staging of node features (merged, 384B-stride, zero-padded)
    cast_xall_kernel<<<(N_NODES * 192 + 255) / 256, 256, 0, stream>>>(x_p, x_f, x_n, xall);

    // radix CSR build: hist -> scan -> block-private scatter -> per-bucket sort
    radix_hist_kernel<<<NB, 256, 0, stream>>>(adj_rows, H);
    scan_part_kernel<<<SCB, 256, 0, stream>>>(H, bsum);
    scan_bsum_kernel<<<1, 512, 0, stream>>>(bsum, rp);
    scan_final_kernel<<<SCB, 256, 0, stream>>>(H, bsum);
    radix_scatter_kernel<<<NB, 256, 0, stream>>>(adj_rows, adj_cols, adj_vals, H, tmp);
    bucket_sort_kernel<<<KBK, 256, 0, stream>>>(tmp, H, rp, cse);

    // layer-1 spmm for all 3 views
    spmm1_all_kernel<<<N_NODES / 4, 256, 0, stream>>>(xall, rp, cse, S_p, S_f, S_n);

    // layer-1 GEMMs -> h_v (fp32)
    int g1 = (N_NODES + 63) / 64;
    gemm1_kernel<<<g1, 256, 0, stream>>>(x_p, S_p, p1_Ws, p1_bs, p1_Wr, p1_br, h_p, 62);
    gemm1_kernel<<<g1, 256, 0, stream>>>(x_f, S_f, f1_Ws, f1_bs, f1_Wr, f1_br, h_f, 37);
    gemm1_kernel<<<g1, 256, 0, stream>>>(x_n, S_n, n1_Ws, n1_bs, n1_Wr, n1_br, h_n, 37);

    // layer-2 GEMMs (matmul-first): Yself fp32 + Yrel bf16 per view
    dim3 g2((N_NODES + 127) / 128, 5);
    gemm2_kernel<<<g2, 256, 0, stream>>>(h_p, p2_Ws, p2_Wr, Ys_p, Yr_p);
    gemm2_kernel<<<g2, 256, 0, stream>>>(h_f, f2_Ws, f2_Wr, Ys_f, Yr_f);
    gemm2_kernel<<<g2, 256, 0, stream>>>(h_n, n2_Ws, n2_Wr, Ys_n, Yr_n);

    // spmm2 (all views) + bias + gated fusion -> z
    spmm2z_all_kernel<<<N_NODES / 4, 256, 0, stream>>>(
        Ys_p, Yr_p, Ys_f, Yr_f, Ys_n, Yr_n, rp, cse,
        p2_bs, p2_br, f2_bs, f2_br, n2_bs, n2_br, gate_W, gate_b, z);

    // edge decoder -> logits
    decoder_kernel<<<(ED_EDGES + 255) / 256, 256, 0, stream>>>(
        z, edge_src, edge_dst, dec_W1, dec_b1, dec_W2, dec_b2, out);
}